// Round 6
// baseline (147.540 us; speedup 1.0000x reference)
//
#include <hip/hip_runtime.h>
#include <math.h>

// ---------------------------------------------------------------------------
// LocalTransformerBlock2d: B=1, C=256, H=W=56 (N=3136), 8 heads x d=32,
// 7x7 local window. fp32 in/out; bf16 MFMA GEMMs.
// 5 stream-ordered kernels:
//   prep(cvt+LN1T) -> qkv -> attn+proj(fused, halo-LDS, +resid) ->
//   fc1(+LN2 fused, +gelu) -> fc2(+resid, transposed out)
// Harness floor: two 268MB poison fills ~88us are inside the timed window
// (R2 evidence: coop kernel 479us vs dur 568). Pipeline budget is what we
// optimize: fewer nodes, less traffic, DMA overlapped with compute.
// ---------------------------------------------------------------------------

typedef unsigned int uint;
typedef unsigned short ushort;
typedef unsigned long long u64;
typedef __attribute__((ext_vector_type(8))) short short8;   // 8 bf16
typedef __attribute__((ext_vector_type(4))) float floatx4;  // MFMA acc
typedef __attribute__((ext_vector_type(4))) unsigned short ushort4v;

#define AS1(p) (const __attribute__((address_space(1))) void*)(p)
#define AS3(p) (__attribute__((address_space(3))) void*)(p)

__device__ __forceinline__ float bf2f(ushort u) {
  union { uint i; float f; } v; v.i = ((uint)u) << 16; return v.f;
}
__device__ __forceinline__ ushort f2bf(float f) {
  union { float f; uint i; } v; v.f = f;
  uint u = v.i;
  return (ushort)((u + 0x7fffu + ((u >> 16) & 1u)) >> 16);
}

// Stage a 64-row x 256-col bf16 panel into LDS with XOR swizzle.
// LDS slot (row, s) holds global col-block (s ^ (row&7)).
__device__ __forceinline__ void stage64(const ushort* src, int kstride,
                                        ushort* dstBase, int tid) {
  const int srow = tid >> 5;                 // 0..7
  const int scb  = (tid & 31) ^ srow;        // permuted 16B block
  const ushort* g = src + (size_t)srow * kstride + scb * 8;
  ushort* d = dstBase + tid * 8;             // wave-uniform base + lane*16B
  #pragma unroll
  for (int r = 0; r < 8; ++r) {
    __builtin_amdgcn_global_load_lds(AS1(g), AS3(d), 16, 0, 0);
    g += 8 * kstride;
    d += 2048;
  }
}

// 8 k-iters over resident K=256 panels; 4 n-subtiles per wave.
__device__ __forceinline__ void compute64(const ushort* As, const ushort* Bs,
                                          int w, int lane, floatx4 acc[4]) {
  const int fm = lane & 15;
  const int q  = lane >> 4;
  const int swz = fm & 7;
  const int arow = (w * 16 + fm) * 256;
  #pragma unroll
  for (int kt = 0; kt < 8; ++kt) {
    const int blk = ((kt * 4 + q) ^ swz) * 8;
    short8 af = *(const short8*)&As[arow + blk];
    #pragma unroll
    for (int nt = 0; nt < 4; ++nt) {
      short8 bfr = *(const short8*)&Bs[(nt * 16 + fm) * 256 + blk];
      acc[nt] = __builtin_amdgcn_mfma_f32_16x16x32_bf16(af, bfr, acc[nt], 0, 0, 0);
    }
  }
}

// ---------------------------------------------------------------------------
// prep: blocks 0..195 LN1+transpose (16 px each); blocks 196+ weight cvt.
// ---------------------------------------------------------------------------
__global__ __launch_bounds__(256) void prep_kernel(
    const float* __restrict__ x, const float* __restrict__ n1w,
    const float* __restrict__ n1b,
    const float* __restrict__ qkvw, const float* __restrict__ projw,
    const float* __restrict__ f1w, const float* __restrict__ f2w,
    float* __restrict__ xT, ushort* __restrict__ t1, ushort* __restrict__ wcat)
{
  const int tid = threadIdx.x;
  const int bid = blockIdx.x;
  if (bid >= 196) {
    int idx = (bid - 196) * 256 + tid;
    float v;
    if (idx < 196608)       v = qkvw[idx];
    else if (idx < 262144)  v = projw[idx - 196608];
    else if (idx < 524288)  v = f1w[idx - 262144];
    else                    v = f2w[idx - 524288];
    wcat[idx] = f2bf(v);
    return;
  }
  __shared__ float tile[256 * 17];
  __shared__ float red[2][16][16];
  __shared__ float mu[16], rsv[16];
  const int n0 = bid * 16;
  const int px = tid & 15, grp = tid >> 4;
  #pragma unroll 4
  for (int it = 0; it < 16; ++it) {
    int c = it * 16 + grp;
    tile[c * 17 + px] = x[(size_t)c * 3136 + n0 + px];
  }
  __syncthreads();
  float s = 0.f, ss = 0.f;
  #pragma unroll
  for (int i = 0; i < 16; ++i) {
    float v = tile[(grp * 16 + i) * 17 + px];
    s += v; ss += v * v;
  }
  red[0][px][grp] = s; red[1][px][grp] = ss;
  __syncthreads();
  if (tid < 16) {
    float s2 = 0.f, ss2 = 0.f;
    #pragma unroll
    for (int g = 0; g < 16; ++g) { s2 += red[0][tid][g]; ss2 += red[1][tid][g]; }
    float m = s2 * (1.f / 256.f);
    float var = ss2 * (1.f / 256.f) - m * m;
    mu[tid] = m;
    rsv[tid] = rsqrtf(var + 1e-5f);
  }
  __syncthreads();
  const float wc = n1w[tid], bc = n1b[tid];
  #pragma unroll 4
  for (int p = 0; p < 16; ++p) {
    float v = tile[tid * 17 + p];
    xT[(size_t)(n0 + p) * 256 + tid] = v;
    t1[(size_t)(n0 + p) * 256 + tid] = f2bf((v - mu[p]) * rsv[p] * wc + bc);
  }
}

// ---------------------------------------------------------------------------
// qkv: [3136,256] @ [768,256]^T + bias (q scaled). grid (12,49).
// ---------------------------------------------------------------------------
__global__ __launch_bounds__(256, 2) void qkv_kernel(
    const ushort* __restrict__ A, const ushort* __restrict__ B,
    const float* __restrict__ bias, ushort* __restrict__ out)
{
  __shared__ ushort As[16384], Bs[16384];
  const int tid = threadIdx.x, lane = tid & 63, w = tid >> 6;
  const int m0 = blockIdx.y * 64, n0 = blockIdx.x * 64;
  floatx4 acc[4] = {{0.f,0.f,0.f,0.f},{0.f,0.f,0.f,0.f},
                    {0.f,0.f,0.f,0.f},{0.f,0.f,0.f,0.f}};
  stage64(A + (size_t)m0 * 256, 256, As, tid);
  stage64(B + (size_t)n0 * 256, 256, Bs, tid);
  asm volatile("s_waitcnt vmcnt(0)" ::: "memory");
  __syncthreads();
  compute64(As, Bs, w, lane, acc);
  const int fm = lane & 15, q4 = (lane >> 4) * 4;
  #pragma unroll
  for (int nt = 0; nt < 4; ++nt)
    #pragma unroll
    for (int r = 0; r < 4; ++r) {
      int m = m0 + w * 16 + q4 + r;
      int n = n0 + nt * 16 + fm;
      float v = acc[nt][r] + bias[n];
      if (n < 256) v *= 0.17677669529663687f;   // 1/sqrt(32) on q
      out[(size_t)m * 768 + n] = f2bf(v);
    }
}

// ---------------------------------------------------------------------------
// attn+proj fused: 4x4 query tile per block (grid 196), 256 threads.
// Phases: halo load -> scores+softmax -> [stage proj chunk0 into dead Kh] PV
//         -> proj GEMM (4 chunks, dbuf through dead pr region) + resid -> x1.
// LDS: Kh 52000 | Vh 51200 | pr 32768 | aas 8448  = 144416 B (1 blk/CU).
// ---------------------------------------------------------------------------
#define ATTN_SMEM 144416

__global__ __launch_bounds__(256, 1) void attnproj_kernel(
    const ushort* __restrict__ qkv, const ushort* __restrict__ pw_bf,
    const float* __restrict__ projb, const float* __restrict__ xT,
    float* __restrict__ x1)
{
  __shared__ __align__(16) char smem[ATTN_SMEM];
  ushort* Kh  = (ushort*)smem;                 // [100][260]
  ushort* Vh  = (ushort*)(smem + 52000);       // [100][256]
  float*  pr  = (float*)(smem + 103200);       // [16][8][64]
  ushort* aas = (ushort*)(smem + 135968);      // [16][264]
  ushort* Bs0 = (ushort*)smem;                 // proj B dbuf (Kh dead)
  ushort* Bs1 = (ushort*)(smem + 103200);      // proj B dbuf (pr dead)

  const int tid = threadIdx.x;
  const int i0 = (blockIdx.x / 14) * 4, j0 = (blockIdx.x % 14) * 4;

  // ---- halo load (zero-fill out-of-image rows) ----
  for (int s = tid; s < 3200; s += 256) {
    int p = s >> 5, ck = s & 31;
    int ii = i0 - 3 + p / 10, jj = j0 - 3 + p % 10;
    if (ii >= 0 && ii < 56 && jj >= 0 && jj < 56) {
      const ushort* kr = qkv + (size_t)(ii * 56 + jj) * 768 + 256 + ck * 8;
      short8 kv = *(const short8*)kr;
      u64 lo = ((const u64*)&kv)[0], hi = ((const u64*)&kv)[1];
      *(u64*)&Kh[p * 260 + ck * 8] = lo;
      *(u64*)&Kh[p * 260 + ck * 8 + 4] = hi;
      *(short8*)&Vh[p * 256 + ck * 8] = *(const short8*)(kr + 256);
    } else {
      *(u64*)&Kh[p * 260 + ck * 8] = 0ull;
      *(u64*)&Kh[p * 260 + ck * 8 + 4] = 0ull;
      short8 z = {0, 0, 0, 0, 0, 0, 0, 0};
      *(short8*)&Vh[p * 256 + ck * 8] = z;
    }
  }
  __syncthreads();

  // ---- scores + softmax: wave wv owns queries 4wv..4wv+3 ----
  const int wv = tid >> 6, lane = tid & 63;
  const int h = lane >> 3, mg = lane & 7;      // head, slot-group
  for (int qq = 0; qq < 4; ++qq) {
    const int p = wv * 4 + qq;
    const int qi = p >> 2, qj = p & 3;
    const int iq = i0 + qi, jq = j0 + qj;
    const ushort* qp = qkv + (size_t)(iq * 56 + jq) * 768 + h * 32;
    float qf[32];
    #pragma unroll
    for (int u = 0; u < 4; ++u) {
      short8 qv = *(const short8*)(qp + u * 8);
      #pragma unroll
      for (int e = 0; e < 8; ++e) qf[u * 8 + e] = bf2f((ushort)qv[e]);
    }
    float sv[7];
    float mx = -1e30f;
    #pragma unroll
    for (int k = 0; k < 7; ++k) {
      int m = mg + 8 * k;
      float s = -1e30f;
      if (m < 49) {
        int mi = m / 7, mj = m % 7;
        int ii = iq + mi - 3, jj = jq + mj - 3;
        if (ii >= 0 && ii < 56 && jj >= 0 && jj < 56) {
          int hrow = (qi + mi) * 10 + (qj + mj);
          const u64* k8 = (const u64*)&Kh[hrow * 260 + h * 32];
          float a = 0.f;
          #pragma unroll
          for (int u = 0; u < 8; ++u) {
            u64 kv = k8[u];
            #pragma unroll
            for (int e = 0; e < 4; ++e)
              a += qf[u * 4 + e] * bf2f((ushort)(kv >> (16 * e)));
          }
          s = a;
        }
      }
      sv[k] = s;
      mx = fmaxf(mx, s);
    }
    mx = fmaxf(mx, __shfl_xor(mx, 1));
    mx = fmaxf(mx, __shfl_xor(mx, 2));
    mx = fmaxf(mx, __shfl_xor(mx, 4));
    float sm = 0.f;
    #pragma unroll
    for (int k = 0; k < 7; ++k) { sv[k] = __expf(sv[k] - mx); sm += sv[k]; }
    sm += __shfl_xor(sm, 1);
    sm += __shfl_xor(sm, 2);
    sm += __shfl_xor(sm, 4);
    float inv = 1.f / sm;
    #pragma unroll
    for (int k = 0; k < 7; ++k) {
      int m = mg + 8 * k;                      // <= 55 < 64
      pr[(p * 8 + h) * 64 + m] = sv[k] * inv;  // invalid slots exact 0
    }
  }
  __syncthreads();     // Kh reads done; pr visible

  // stage proj chunk 0 into dead Kh region; DMA overlaps PV compute
  stage64(pw_bf, 256, Bs0, tid);

  // ---- PV: thread = (qsel, 8-channel group); 2 passes cover 16 queries ----
  {
    const int qsel = tid >> 5, cg = tid & 31, hh = cg >> 2;
    #pragma unroll
    for (int pass = 0; pass < 2; ++pass) {
      const int p = pass * 8 + qsel;
      const int qi = p >> 2, qj = p & 3;
      float acc8[8] = {0, 0, 0, 0, 0, 0, 0, 0};
      #pragma unroll
      for (int mi = 0; mi < 7; ++mi)
        #pragma unroll
        for (int mj = 0; mj < 7; ++mj) {
          int m = mi * 7 + mj;
          int hrow = (qi + mi) * 10 + (qj + mj);
          float pm = pr[(p * 8 + hh) * 64 + m];  // 0 for out-of-image
          short8 v8 = *(const short8*)&Vh[hrow * 256 + cg * 8];
          #pragma unroll
          for (int e = 0; e < 8; ++e)
            acc8[e] += pm * bf2f((ushort)v8[e]);
        }
      short8 o;
      #pragma unroll
      for (int e = 0; e < 8; ++e) o[e] = (short)f2bf(acc8[e]);
      *(short8*)&aas[p * 264 + cg * 8] = o;
    }
  }
  __syncthreads();     // aas visible; pr dead from here

  // ---- proj: x1[16px][256] = aas @ pw^T + bias + resid(xT). 4 n-chunks. ----
  const int fm = lane & 15, q = lane >> 4, q4 = q * 4;
  for (int c = 0; c < 4; ++c) {
    if (c > 0) __syncthreads();                // compute(c-1) done everywhere
    if (c < 3) {
      stage64(pw_bf + (size_t)(c + 1) * 64 * 256, 256, (c & 1) ? Bs0 : Bs1, tid);
      asm volatile("s_waitcnt vmcnt(8)" ::: "memory");   // chunk c landed
    } else {
      asm volatile("s_waitcnt vmcnt(0)" ::: "memory");
    }
    __syncthreads();
    const ushort* Bc = (c & 1) ? Bs1 : Bs0;
    floatx4 acc = {0.f, 0.f, 0.f, 0.f};
    const int rr = wv * 16 + fm;               // B row within chunk
    #pragma unroll
    for (int kt = 0; kt < 8; ++kt) {
      short8 af = *(const short8*)&aas[fm * 264 + kt * 32 + q * 8];
      short8 bfr = *(const short8*)&Bc[rr * 256 + (((kt * 4 + q) ^ (fm & 7))) * 8];
      acc = __builtin_amdgcn_mfma_f32_16x16x32_bf16(af, bfr, acc, 0, 0, 0);
    }
    const int ch = c * 64 + wv * 16 + fm;      // output channel
    #pragma unroll
    for (int r = 0; r < 4; ++r) {
      int p = q4 + r;                          // local pixel 0..15
      int n = (i0 + (p >> 2)) * 56 + j0 + (p & 3);
      x1[(size_t)n * 256 + ch] = acc[r] + projb[ch] + xT[(size_t)n * 256 + ch];
    }
  }
}

// ---------------------------------------------------------------------------
// fc1 (+LN2 fused): A = LN2(x1[m0:m0+64][0:256]) normalized in-block,
// D = A @ f1w[1024,256]^T + bias, gelu -> h1 bf16. grid (16,49).
// ---------------------------------------------------------------------------
__global__ __launch_bounds__(256, 2) void fc1_kernel(
    const float* __restrict__ x1, const ushort* __restrict__ B,
    const float* __restrict__ n2w, const float* __restrict__ n2b,
    const float* __restrict__ bias, ushort* __restrict__ out)
{
  __shared__ ushort As[16384], Bs[16384];
  __shared__ float stats[128];               // 64 rows x {mu, rs}
  const int tid = threadIdx.x, lane = tid & 63, w = tid >> 6;
  const int m0 = blockIdx.y * 64, n0 = blockIdx.x * 64;

  stage64(B + (size_t)n0 * 256, 256, Bs, tid);   // B DMA in flight during LN

  {
    const int r = tid >> 2, seg = tid & 3;
    const float* src = x1 + (size_t)(m0 + r) * 256 + seg * 64;
    float s = 0.f, ss = 0.f;
    #pragma unroll
    for (int i = 0; i < 16; ++i) {
      floatx4 v = *(const floatx4*)(src + i * 4);
      s += v[0] + v[1] + v[2] + v[3];
      ss += v[0]*v[0] + v[1]*v[1] + v[2]*v[2] + v[3]*v[3];
    }
    s += __shfl_xor(s, 1); ss += __shfl_xor(ss, 1);
    s += __shfl_xor(s, 2); ss += __shfl_xor(ss, 2);
    if (seg == 0) {
      float mu = s * (1.f / 256.f);
      float var = ss * (1.f / 256.f) - mu * mu;
      stats[r * 2] = mu;
      stats[r * 2 + 1] = rsqrtf(var + 1e-5f);
    }
  }
  __syncthreads();
  #pragma unroll
  for (int k = 0; k < 8; ++k) {
    int s = tid + k * 256;
    int row = s >> 5, cb = s & 31;
    int gb = cb ^ (row & 7);
    float mu = stats[row * 2], rs = stats[row * 2 + 1];
    const float* src = x1 + (size_t)(m0 + row) * 256 + gb * 8;
    floatx4 a = *(const floatx4*)(src);
    floatx4 b2 = *(const floatx4*)(src + 4);
    floatx4 w1 = *(const floatx4*)(n2w + gb * 8);
    floatx4 w2 = *(const floatx4*)(n2w + gb * 8 + 4);
    floatx4 b1v = *(const floatx4*)(n2b + gb * 8);
    floatx4 b2v = *(const floatx4*)(n2b + gb * 8 + 4);
    short8 o;
    #pragma unroll
    for (int e = 0; e < 4; ++e) {
      o[e]     = (short)f2bf((a[e]  - mu) * rs * w1[e] + b1v[e]);
      o[e + 4] = (short)f2bf((b2[e] - mu) * rs * w2[e] + b2v[e]);
    }
    *(short8*)&As[row * 256 + cb * 8] = o;
  }
  asm volatile("s_waitcnt vmcnt(0)" ::: "memory");
  __syncthreads();

  floatx4 acc[4] = {{0.f,0.f,0.f,0.f},{0.f,0.f,0.f,0.f},
                    {0.f,0.f,0.f,0.f},{0.f,0.f,0.f,0.f}};
  compute64(As, Bs, w, lane, acc);
  const int fm = lane & 15, q4 = (lane >> 4) * 4;
  #pragma unroll
  for (int nt = 0; nt < 4; ++nt)
    #pragma unroll
    for (int r = 0; r < 4; ++r) {
      int m = m0 + w * 16 + q4 + r;
      int n = n0 + nt * 16 + fm;
      float v = acc[nt][r] + bias[n];
      v = 0.5f * v * (1.0f + erff(v * 0.70710678118654752f));
      out[(size_t)m * 1024 + n] = f2bf(v);
    }
}

// ---------------------------------------------------------------------------
// fc2: out[C][N] = f2w[256,1024] @ h1[3136,1024]^T + bias + x1^T. grid (49,4).
// ---------------------------------------------------------------------------
__global__ __launch_bounds__(256, 2) void fc2_kernel(
    const ushort* __restrict__ A, const ushort* __restrict__ B,
    const float* __restrict__ bias, const float* __restrict__ x1,
    float* __restrict__ outf)
{
  __shared__ ushort As[16384], Bs[16384];
  const int tid = threadIdx.x, lane = tid & 63, w = tid >> 6;
  const int m0 = blockIdx.y * 64, n0 = blockIdx.x * 64;
  floatx4 acc[4] = {{0.f,0.f,0.f,0.f},{0.f,0.f,0.f,0.f},
                    {0.f,0.f,0.f,0.f},{0.f,0.f,0.f,0.f}};
  for (int kc = 0; kc < 4; ++kc) {
    if (kc) __syncthreads();
    stage64(A + (size_t)m0 * 1024 + kc * 256, 1024, As, tid);
    stage64(B + (size_t)n0 * 1024 + kc * 256, 1024, Bs, tid);
    asm volatile("s_waitcnt vmcnt(0)" ::: "memory");
    __syncthreads();
    compute64(As, Bs, w, lane, acc);
  }
  const int fm = lane & 15, q4 = (lane >> 4) * 4;
  #pragma unroll
  for (int nt = 0; nt < 4; ++nt)
    #pragma unroll
    for (int r = 0; r < 4; ++r) {
      int m = m0 + w * 16 + q4 + r;       // channel
      int n = n0 + nt * 16 + fm;          // pixel
      outf[(size_t)m * 3136 + n] = acc[nt][r] + bias[m] + x1[(size_t)n * 256 + m];
    }
}

// ---------------------------------------------------------------------------
extern "C" void kernel_launch(void* const* d_in, const int* in_sizes, int n_in,
                              void* d_out, int out_size, void* d_ws, size_t ws_size,
                              hipStream_t stream) {
  const float* x     = (const float*)d_in[0];
  const float* n1w   = (const float*)d_in[1];
  const float* n1b   = (const float*)d_in[2];
  const float* qkvw  = (const float*)d_in[3];
  const float* qkvb  = (const float*)d_in[4];
  const float* projw = (const float*)d_in[5];
  const float* projb = (const float*)d_in[6];
  const float* n2w   = (const float*)d_in[7];
  const float* n2b   = (const float*)d_in[8];
  const float* f1w   = (const float*)d_in[9];
  const float* f1b   = (const float*)d_in[10];
  const float* f2w   = (const float*)d_in[11];
  const float* f2b   = (const float*)d_in[12];

  char* ws = (char*)d_ws;
  ushort* wcat = (ushort*)(ws + 0);            // 786432 bf16
  float*  xT   = (float*)(ws + 1572864);       // 802816 f32 (LN1 input copy)
  ushort* t    = (ushort*)(ws + 4784128);      // 802816 bf16 (t1)
  ushort* qh   = (ushort*)(ws + 6389760);      // qkv [3136][768], then h1 [3136][1024]
  float*  x1   = (float*)(ws + 12812288);      // 802816 f32 (post-attn resid)

  const ushort* qw_bf = wcat;
  const ushort* pw_bf = wcat + 196608;
  const ushort* f1_bf = wcat + 262144;
  const ushort* f2_bf = wcat + 524288;
  float* outf = (float*)d_out;

  hipLaunchKernelGGL(prep_kernel, dim3(3268), dim3(256), 0, stream,
                     x, n1w, n1b, qkvw, projw, f1w, f2w, xT, t, wcat);
  hipLaunchKernelGGL(qkv_kernel, dim3(12, 49), dim3(256), 0, stream,
                     t, qw_bf, qkvb, qh);
  hipLaunchKernelGGL(attnproj_kernel, dim3(196), dim3(256), 0, stream,
                     qh, pw_bf, projb, xT, x1);
  hipLaunchKernelGGL(fc1_kernel, dim3(16, 49), dim3(256), 0, stream,
                     x1, f1_bf, n2w, n2b, f1b, qh);
  hipLaunchKernelGGL(fc2_kernel, dim3(49, 4), dim3(256), 0, stream,
                     f2_bf, qh, f2b, x1, outf);
}

// Round 7
// 145.133 us; speedup vs baseline: 1.0166x; 1.0166x over previous
//
#include <hip/hip_runtime.h>
#include <math.h>

// ---------------------------------------------------------------------------
// LocalTransformerBlock2d: B=1, C=256, H=W=56 (N=3136), 8 heads x d=32,
// 7x7 local window. fp32 in/out; bf16 MFMA GEMMs.
// 4 stream-ordered kernels:
//   prep(cvt+LN1T) -> qkv -> attn+proj(fused, halo-LDS, +resid) ->
//   mlp(LN2+fc1+gelu+fc2+resid fused per 16-pixel block)
// Harness floor: two 268MB poison fills ~88us inside the timed window (R2).
// R6 lesson: fusion must kill redundant traffic, not just a node. mlp fusion
// removes fc1's 16x re-read of x1 (205MB L2) and the h1 global round-trip.
// ---------------------------------------------------------------------------

typedef unsigned int uint;
typedef unsigned short ushort;
typedef unsigned long long u64;
typedef __attribute__((ext_vector_type(8))) short short8;   // 8 bf16
typedef __attribute__((ext_vector_type(4))) float floatx4;  // MFMA acc
typedef __attribute__((ext_vector_type(4))) unsigned short ushort4v;

#define AS1(p) (const __attribute__((address_space(1))) void*)(p)
#define AS3(p) (__attribute__((address_space(3))) void*)(p)

__device__ __forceinline__ float bf2f(ushort u) {
  union { uint i; float f; } v; v.i = ((uint)u) << 16; return v.f;
}
__device__ __forceinline__ ushort f2bf(float f) {
  union { float f; uint i; } v; v.f = f;
  uint u = v.i;
  return (ushort)((u + 0x7fffu + ((u >> 16) & 1u)) >> 16);
}

// Stage a 64-row x 256-col bf16 panel into LDS with XOR swizzle.
// LDS slot (row, s) holds global col-block (s ^ (row&7)).
__device__ __forceinline__ void stage64(const ushort* src, int kstride,
                                        ushort* dstBase, int tid) {
  const int srow = tid >> 5;                 // 0..7
  const int scb  = (tid & 31) ^ srow;        // permuted 16B block
  const ushort* g = src + (size_t)srow * kstride + scb * 8;
  ushort* d = dstBase + tid * 8;             // wave-uniform base + lane*16B
  #pragma unroll
  for (int r = 0; r < 8; ++r) {
    __builtin_amdgcn_global_load_lds(AS1(g), AS3(d), 16, 0, 0);
    g += 8 * kstride;
    d += 2048;
  }
}

// 8 k-iters over resident K=256 panels; 4 n-subtiles per wave.
__device__ __forceinline__ void compute64(const ushort* As, const ushort* Bs,
                                          int w, int lane, floatx4 acc[4]) {
  const int fm = lane & 15;
  const int q  = lane >> 4;
  const int swz = fm & 7;
  const int arow = (w * 16 + fm) * 256;
  #pragma unroll
  for (int kt = 0; kt < 8; ++kt) {
    const int blk = ((kt * 4 + q) ^ swz) * 8;
    short8 af = *(const short8*)&As[arow + blk];
    #pragma unroll
    for (int nt = 0; nt < 4; ++nt) {
      short8 bfr = *(const short8*)&Bs[(nt * 16 + fm) * 256 + blk];
      acc[nt] = __builtin_amdgcn_mfma_f32_16x16x32_bf16(af, bfr, acc[nt], 0, 0, 0);
    }
  }
}

// ---------------------------------------------------------------------------
// prep: blocks 0..195 LN1+transpose (16 px each); blocks 196+ weight cvt.
// ---------------------------------------------------------------------------
__global__ __launch_bounds__(256) void prep_kernel(
    const float* __restrict__ x, const float* __restrict__ n1w,
    const float* __restrict__ n1b,
    const float* __restrict__ qkvw, const float* __restrict__ projw,
    const float* __restrict__ f1w, const float* __restrict__ f2w,
    float* __restrict__ xT, ushort* __restrict__ t1, ushort* __restrict__ wcat)
{
  const int tid = threadIdx.x;
  const int bid = blockIdx.x;
  if (bid >= 196) {
    int idx = (bid - 196) * 256 + tid;
    float v;
    if (idx < 196608)       v = qkvw[idx];
    else if (idx < 262144)  v = projw[idx - 196608];
    else if (idx < 524288)  v = f1w[idx - 262144];
    else                    v = f2w[idx - 524288];
    wcat[idx] = f2bf(v);
    return;
  }
  __shared__ float tile[256 * 17];
  __shared__ float red[2][16][16];
  __shared__ float mu[16], rsv[16];
  const int n0 = bid * 16;
  const int px = tid & 15, grp = tid >> 4;
  #pragma unroll 4
  for (int it = 0; it < 16; ++it) {
    int c = it * 16 + grp;
    tile[c * 17 + px] = x[(size_t)c * 3136 + n0 + px];
  }
  __syncthreads();
  float s = 0.f, ss = 0.f;
  #pragma unroll
  for (int i = 0; i < 16; ++i) {
    float v = tile[(grp * 16 + i) * 17 + px];
    s += v; ss += v * v;
  }
  red[0][px][grp] = s; red[1][px][grp] = ss;
  __syncthreads();
  if (tid < 16) {
    float s2 = 0.f, ss2 = 0.f;
    #pragma unroll
    for (int g = 0; g < 16; ++g) { s2 += red[0][tid][g]; ss2 += red[1][tid][g]; }
    float m = s2 * (1.f / 256.f);
    float var = ss2 * (1.f / 256.f) - m * m;
    mu[tid] = m;
    rsv[tid] = rsqrtf(var + 1e-5f);
  }
  __syncthreads();
  const float wc = n1w[tid], bc = n1b[tid];
  #pragma unroll 4
  for (int p = 0; p < 16; ++p) {
    float v = tile[tid * 17 + p];
    xT[(size_t)(n0 + p) * 256 + tid] = v;
    t1[(size_t)(n0 + p) * 256 + tid] = f2bf((v - mu[p]) * rsv[p] * wc + bc);
  }
}

// ---------------------------------------------------------------------------
// qkv: [3136,256] @ [768,256]^T + bias (q scaled). grid (12,49).
// ---------------------------------------------------------------------------
__global__ __launch_bounds__(256, 2) void qkv_kernel(
    const ushort* __restrict__ A, const ushort* __restrict__ B,
    const float* __restrict__ bias, ushort* __restrict__ out)
{
  __shared__ ushort As[16384], Bs[16384];
  const int tid = threadIdx.x, lane = tid & 63, w = tid >> 6;
  const int m0 = blockIdx.y * 64, n0 = blockIdx.x * 64;
  floatx4 acc[4] = {{0.f,0.f,0.f,0.f},{0.f,0.f,0.f,0.f},
                    {0.f,0.f,0.f,0.f},{0.f,0.f,0.f,0.f}};
  stage64(A + (size_t)m0 * 256, 256, As, tid);
  stage64(B + (size_t)n0 * 256, 256, Bs, tid);
  asm volatile("s_waitcnt vmcnt(0)" ::: "memory");
  __syncthreads();
  compute64(As, Bs, w, lane, acc);
  const int fm = lane & 15, q4 = (lane >> 4) * 4;
  #pragma unroll
  for (int nt = 0; nt < 4; ++nt)
    #pragma unroll
    for (int r = 0; r < 4; ++r) {
      int m = m0 + w * 16 + q4 + r;
      int n = n0 + nt * 16 + fm;
      float v = acc[nt][r] + bias[n];
      if (n < 256) v *= 0.17677669529663687f;   // 1/sqrt(32) on q
      out[(size_t)m * 768 + n] = f2bf(v);
    }
}

// ---------------------------------------------------------------------------
// attn+proj fused: 4x4 query tile per block (grid 196), 256 threads.
// LDS: Kh 52000 | Vh 51200 | pr 32768 | aas 8448 = 144416 B (1 blk/CU).
// ---------------------------------------------------------------------------
#define ATTN_SMEM 144416

__global__ __launch_bounds__(256, 1) void attnproj_kernel(
    const ushort* __restrict__ qkv, const ushort* __restrict__ pw_bf,
    const float* __restrict__ projb, const float* __restrict__ xT,
    float* __restrict__ x1)
{
  __shared__ __align__(16) char smem[ATTN_SMEM];
  ushort* Kh  = (ushort*)smem;                 // [100][260]
  ushort* Vh  = (ushort*)(smem + 52000);       // [100][256]
  float*  pr  = (float*)(smem + 103200);       // [16][8][64]
  ushort* aas = (ushort*)(smem + 135968);      // [16][264]
  ushort* Bs0 = (ushort*)smem;                 // proj B dbuf (Kh dead)
  ushort* Bs1 = (ushort*)(smem + 103200);      // proj B dbuf (pr dead)

  const int tid = threadIdx.x;
  const int i0 = (blockIdx.x / 14) * 4, j0 = (blockIdx.x % 14) * 4;

  // ---- halo load (zero-fill out-of-image rows) ----
  for (int s = tid; s < 3200; s += 256) {
    int p = s >> 5, ck = s & 31;
    int ii = i0 - 3 + p / 10, jj = j0 - 3 + p % 10;
    if (ii >= 0 && ii < 56 && jj >= 0 && jj < 56) {
      const ushort* kr = qkv + (size_t)(ii * 56 + jj) * 768 + 256 + ck * 8;
      short8 kv = *(const short8*)kr;
      u64 lo = ((const u64*)&kv)[0], hi = ((const u64*)&kv)[1];
      *(u64*)&Kh[p * 260 + ck * 8] = lo;
      *(u64*)&Kh[p * 260 + ck * 8 + 4] = hi;
      *(short8*)&Vh[p * 256 + ck * 8] = *(const short8*)(kr + 256);
    } else {
      *(u64*)&Kh[p * 260 + ck * 8] = 0ull;
      *(u64*)&Kh[p * 260 + ck * 8 + 4] = 0ull;
      short8 z = {0, 0, 0, 0, 0, 0, 0, 0};
      *(short8*)&Vh[p * 256 + ck * 8] = z;
    }
  }
  __syncthreads();

  // ---- scores + softmax: wave wv owns queries 4wv..4wv+3 ----
  const int wv = tid >> 6, lane = tid & 63;
  const int h = lane >> 3, mg = lane & 7;      // head, slot-group
  for (int qq = 0; qq < 4; ++qq) {
    const int p = wv * 4 + qq;
    const int qi = p >> 2, qj = p & 3;
    const int iq = i0 + qi, jq = j0 + qj;
    const ushort* qp = qkv + (size_t)(iq * 56 + jq) * 768 + h * 32;
    float qf[32];
    #pragma unroll
    for (int u = 0; u < 4; ++u) {
      short8 qv = *(const short8*)(qp + u * 8);
      #pragma unroll
      for (int e = 0; e < 8; ++e) qf[u * 8 + e] = bf2f((ushort)qv[e]);
    }
    float sv[7];
    float mx = -1e30f;
    #pragma unroll
    for (int k = 0; k < 7; ++k) {
      int m = mg + 8 * k;
      float s = -1e30f;
      if (m < 49) {
        int mi = m / 7, mj = m % 7;
        int ii = iq + mi - 3, jj = jq + mj - 3;
        if (ii >= 0 && ii < 56 && jj >= 0 && jj < 56) {
          int hrow = (qi + mi) * 10 + (qj + mj);
          const u64* k8 = (const u64*)&Kh[hrow * 260 + h * 32];
          float a = 0.f;
          #pragma unroll
          for (int u = 0; u < 8; ++u) {
            u64 kv = k8[u];
            #pragma unroll
            for (int e = 0; e < 4; ++e)
              a += qf[u * 4 + e] * bf2f((ushort)(kv >> (16 * e)));
          }
          s = a;
        }
      }
      sv[k] = s;
      mx = fmaxf(mx, s);
    }
    mx = fmaxf(mx, __shfl_xor(mx, 1));
    mx = fmaxf(mx, __shfl_xor(mx, 2));
    mx = fmaxf(mx, __shfl_xor(mx, 4));
    float sm = 0.f;
    #pragma unroll
    for (int k = 0; k < 7; ++k) { sv[k] = __expf(sv[k] - mx); sm += sv[k]; }
    sm += __shfl_xor(sm, 1);
    sm += __shfl_xor(sm, 2);
    sm += __shfl_xor(sm, 4);
    float inv = 1.f / sm;
    #pragma unroll
    for (int k = 0; k < 7; ++k) {
      int m = mg + 8 * k;                      // <= 55 < 64
      pr[(p * 8 + h) * 64 + m] = sv[k] * inv;  // invalid slots exact 0
    }
  }
  __syncthreads();     // Kh reads done; pr visible

  // stage proj chunk 0 into dead Kh region; DMA overlaps PV compute
  stage64(pw_bf, 256, Bs0, tid);

  // ---- PV: thread = (qsel, 8-channel group); 2 passes cover 16 queries ----
  {
    const int qsel = tid >> 5, cg = tid & 31, hh = cg >> 2;
    #pragma unroll
    for (int pass = 0; pass < 2; ++pass) {
      const int p = pass * 8 + qsel;
      const int qi = p >> 2, qj = p & 3;
      float acc8[8] = {0, 0, 0, 0, 0, 0, 0, 0};
      #pragma unroll
      for (int mi = 0; mi < 7; ++mi)
        #pragma unroll
        for (int mj = 0; mj < 7; ++mj) {
          int m = mi * 7 + mj;
          int hrow = (qi + mi) * 10 + (qj + mj);
          float pm = pr[(p * 8 + hh) * 64 + m];  // 0 for out-of-image
          short8 v8 = *(const short8*)&Vh[hrow * 256 + cg * 8];
          #pragma unroll
          for (int e = 0; e < 8; ++e)
            acc8[e] += pm * bf2f((ushort)v8[e]);
        }
      short8 o;
      #pragma unroll
      for (int e = 0; e < 8; ++e) o[e] = (short)f2bf(acc8[e]);
      *(short8*)&aas[p * 264 + cg * 8] = o;
    }
  }
  __syncthreads();     // aas visible; pr dead from here

  // ---- proj: x1[16px][256] = aas @ pw^T + bias + resid(xT). 4 n-chunks. ----
  const int fm = lane & 15, q = lane >> 4, q4 = q * 4;
  for (int c = 0; c < 4; ++c) {
    if (c > 0) __syncthreads();                // compute(c-1) done everywhere
    if (c < 3) {
      stage64(pw_bf + (size_t)(c + 1) * 64 * 256, 256, (c & 1) ? Bs0 : Bs1, tid);
      asm volatile("s_waitcnt vmcnt(8)" ::: "memory");   // chunk c landed
    } else {
      asm volatile("s_waitcnt vmcnt(0)" ::: "memory");
    }
    __syncthreads();
    const ushort* Bc = (c & 1) ? Bs1 : Bs0;
    floatx4 acc = {0.f, 0.f, 0.f, 0.f};
    const int rr = wv * 16 + fm;               // B row within chunk
    #pragma unroll
    for (int kt = 0; kt < 8; ++kt) {
      short8 af = *(const short8*)&aas[fm * 264 + kt * 32 + q * 8];
      short8 bfr = *(const short8*)&Bc[rr * 256 + (((kt * 4 + q) ^ (fm & 7))) * 8];
      acc = __builtin_amdgcn_mfma_f32_16x16x32_bf16(af, bfr, acc, 0, 0, 0);
    }
    const int ch = c * 64 + wv * 16 + fm;      // output channel
    #pragma unroll
    for (int r = 0; r < 4; ++r) {
      int p = q4 + r;                          // local pixel 0..15
      int n = (i0 + (p >> 2)) * 56 + j0 + (p & 3);
      x1[(size_t)n * 256 + ch] = acc[r] + projb[ch] + xT[(size_t)n * 256 + ch];
    }
  }
}

// ---------------------------------------------------------------------------
// mlp: block = 16 pixels (grid 196), 256 thr. LN2+fc1+gelu+fc2+resid fused.
// x1 read once into regs (also the fc2 residual); t2/h in LDS; weights
// streamed per-wave via 2x4KB slab dbuf (global_load_lds, per-wave vmcnt,
// ZERO barriers inside GEMM loops; waves own exclusive h columns / out rows).
// LDS: t2s 8K + h 32K + slabs 32K + stats ~0.7K = 74.4K -> 2 blk/CU.
// ---------------------------------------------------------------------------
__global__ __launch_bounds__(256, 2) void mlp_kernel(
    const float* __restrict__ x1, const ushort* __restrict__ f1_bf,
    const float* __restrict__ f1b, const ushort* __restrict__ f2_bf,
    const float* __restrict__ f2b, const float* __restrict__ n2w,
    const float* __restrict__ n2b, float* __restrict__ outf)
{
  __shared__ ushort t2s[16 * 256];       // [px][slot^(px&7)] bf16
  __shared__ ushort hbuf[16 * 1024];     // [px][slot^(px&7)] bf16
  __shared__ ushort slab[4][2][2048];    // per-wave dbuf, 2 x 4KB (64r x 4blk)
  __shared__ float pstat[4][16][2];
  __shared__ float stats[16][2];

  const int tid = threadIdx.x;
  const int n0 = blockIdx.x * 16;
  const int w = tid >> 6;
  const int lane = tid & 63;
  const int fm = lane & 15;              // px in A/B frags
  const int px = tid & 15;
  const int q = (lane >> 4) & 3;
  const int l4 = lane >> 2, lb = lane & 3;   // staging row-part / block

  // ---- Phase A: load x1 (kept in regs = fc2 residual), LN2 -> t2s ----
  floatx4 xv[4];
  #pragma unroll
  for (int mc = 0; mc < 4; ++mc)
    xv[mc] = *(const floatx4*)(x1 + (size_t)(n0 + px) * 256 + w * 64 + mc * 16 + q * 4);
  float s = 0.f, ss = 0.f;
  #pragma unroll
  for (int mc = 0; mc < 4; ++mc)
    #pragma unroll
    for (int e = 0; e < 4; ++e) { s += xv[mc][e]; ss += xv[mc][e] * xv[mc][e]; }
  s += __shfl_xor(s, 16); ss += __shfl_xor(ss, 16);
  s += __shfl_xor(s, 32); ss += __shfl_xor(ss, 32);
  if (lane < 16) { pstat[w][px][0] = s; pstat[w][px][1] = ss; }
  __syncthreads();
  if (tid < 16) {
    float s2 = 0.f, ss2 = 0.f;
    #pragma unroll
    for (int ww = 0; ww < 4; ++ww) { s2 += pstat[ww][tid][0]; ss2 += pstat[ww][tid][1]; }
    float mu = s2 * (1.f / 256.f);
    float var = ss2 * (1.f / 256.f) - mu * mu;
    stats[tid][0] = mu;
    stats[tid][1] = rsqrtf(var + 1e-5f);
  }
  __syncthreads();
  {
    float mu = stats[px][0], rs = stats[px][1];
    #pragma unroll
    for (int mc = 0; mc < 4; ++mc) {
      int ch0 = w * 64 + mc * 16 + q * 4;
      ushort4v o;
      #pragma unroll
      for (int e = 0; e < 4; ++e)
        o[e] = f2bf((xv[mc][e] - mu) * rs * n2w[ch0 + e] + n2b[ch0 + e]);
      int slot = (ch0 >> 3) ^ (px & 7);
      *(ushort4v*)&t2s[px * 256 + slot * 8 + (ch0 & 7)] = o;
    }
  }
  // preload fc1 bias for this wave's chunks {w, w+4, w+8, w+12}
  float f1br[4][4];
  #pragma unroll
  for (int ci = 0; ci < 4; ++ci)
    #pragma unroll
    for (int nt = 0; nt < 4; ++nt)
      f1br[ci][nt] = f1b[(ci * 4 + w) * 64 + nt * 16 + fm];
  __syncthreads();   // t2s complete

  ushort* sb0 = slab[w][0];
  ushort* sb1 = slab[w][1];

  // ---- fc1: wave w computes h columns of chunks {w,4+w,8+w,12+w} ----
  {
    // stage slab (64 rows x 4 k-blocks = 4KB) of chunk nc, k-iter kt
    #define STAGE_F1(nc, kt, buf) do { \
      _Pragma("unroll") \
      for (int i_ = 0; i_ < 4; ++i_) { \
        int row_ = i_ * 16 + l4; \
        const ushort* g_ = f1_bf + (size_t)((nc) * 64 + row_) * 256 + (kt) * 32 + (lb ^ (row_ & 3)) * 8; \
        __builtin_amdgcn_global_load_lds(AS1(g_), AS3((buf) + i_ * 512 + lane * 8), 16, 0, 0); \
      } } while (0)

    floatx4 fa[4] = {{0.f,0.f,0.f,0.f},{0.f,0.f,0.f,0.f},
                     {0.f,0.f,0.f,0.f},{0.f,0.f,0.f,0.f}};
    STAGE_F1(w, 0, sb0);
    for (int sidx = 0; sidx < 32; ++sidx) {
      const int kt = sidx & 7;
      const int nc = (sidx >> 3) * 4 + w;
      ushort* cur = (sidx & 1) ? sb1 : sb0;
      ushort* nxt = (sidx & 1) ? sb0 : sb1;
      if (sidx < 31) {
        int s1 = sidx + 1;
        STAGE_F1((s1 >> 3) * 4 + w, s1 & 7, nxt);
        asm volatile("s_waitcnt vmcnt(4)" ::: "memory");
      } else {
        asm volatile("s_waitcnt vmcnt(0)" ::: "memory");
      }
      short8 af = *(const short8*)&t2s[fm * 256 + (((kt * 4 + q) ^ (fm & 7)) * 8)];
      #pragma unroll
      for (int nt = 0; nt < 4; ++nt) {
        int r = nt * 16 + fm;
        short8 bfr = *(const short8*)&cur[r * 32 + (q ^ (r & 3)) * 8];
        fa[nt] = __builtin_amdgcn_mfma_f32_16x16x32_bf16(af, bfr, fa[nt], 0, 0, 0);
      }
      if (kt == 7) {
        #pragma unroll
        for (int nt = 0; nt < 4; ++nt) {
          int hc = nc * 64 + nt * 16 + fm;
          int hslotbase = (hc >> 3);
          #pragma unroll
          for (int r4 = 0; r4 < 4; ++r4) {
            int prow = q * 4 + r4;
            float v = fa[nt][r4] + f1br[sidx >> 3][nt];
            v = 0.5f * v * (1.0f + erff(v * 0.70710678118654752f));
            hbuf[prow * 1024 + ((hslotbase ^ (prow & 7)) * 8) + (hc & 7)] = f2bf(v);
            fa[nt][r4] = 0.f;
          }
        }
      }
    }
    #undef STAGE_F1
  }
  __syncthreads();   // h complete (cross-wave columns)

  // ---- fc2: wave w computes out channels w*64..w*64+63 for all 16 px ----
  {
    #define STAGE_F2(kt, buf) do { \
      _Pragma("unroll") \
      for (int i_ = 0; i_ < 4; ++i_) { \
        int row_ = i_ * 16 + l4; \
        const ushort* g_ = f2_bf + (size_t)(w * 64 + row_) * 1024 + (kt) * 32 + (lb ^ (row_ & 3)) * 8; \
        __builtin_amdgcn_global_load_lds(AS1(g_), AS3((buf) + i_ * 512 + lane * 8), 16, 0, 0); \
      } } while (0)

    floatx4 ga[4] = {{0.f,0.f,0.f,0.f},{0.f,0.f,0.f,0.f},
                     {0.f,0.f,0.f,0.f},{0.f,0.f,0.f,0.f}};
    STAGE_F2(0, sb0);
    for (int kt = 0; kt < 32; ++kt) {
      ushort* cur = (kt & 1) ? sb1 : sb0;
      ushort* nxt = (kt & 1) ? sb0 : sb1;
      if (kt < 31) {
        STAGE_F2(kt + 1, nxt);
        asm volatile("s_waitcnt vmcnt(4)" ::: "memory");
      } else {
        asm volatile("s_waitcnt vmcnt(0)" ::: "memory");
      }
      short8 bfr = *(const short8*)&hbuf[fm * 1024 + (((kt * 4 + q) ^ (fm & 7)) * 8)];
      #pragma unroll
      for (int mt = 0; mt < 4; ++mt) {
        int r = mt * 16 + fm;
        short8 af = *(const short8*)&cur[r * 32 + (q ^ (r & 3)) * 8];
        ga[mt] = __builtin_amdgcn_mfma_f32_16x16x32_bf16(af, bfr, ga[mt], 0, 0, 0);
      }
    }
    #undef STAGE_F2
    // epilogue: D col = lane&15 = px, row = q*4+r4 = ch-within-subtile.
    // residual = xv[mt][r4] (mapping chosen in Phase A to match exactly).
    #pragma unroll
    for (int mt = 0; mt < 4; ++mt) {
      #pragma unroll
      for (int r4 = 0; r4 < 4; ++r4) {
        int ch = w * 64 + mt * 16 + q * 4 + r4;
        float v = ga[mt][r4] + f2b[ch] + xv[mt][r4];
        outf[(size_t)ch * 3136 + n0 + fm] = v;
      }
    }
  }
}

// ---------------------------------------------------------------------------
extern "C" void kernel_launch(void* const* d_in, const int* in_sizes, int n_in,
                              void* d_out, int out_size, void* d_ws, size_t ws_size,
                              hipStream_t stream) {
  const float* x     = (const float*)d_in[0];
  const float* n1w   = (const float*)d_in[1];
  const float* n1b   = (const float*)d_in[2];
  const float* qkvw  = (const float*)d_in[3];
  const float* qkvb  = (const float*)d_in[4];
  const float* projw = (const float*)d_in[5];
  const float* projb = (const float*)d_in[6];
  const float* n2w   = (const float*)d_in[7];
  const float* n2b   = (const float*)d_in[8];
  const float* f1w   = (const float*)d_in[9];
  const float* f1b   = (const float*)d_in[10];
  const float* f2w   = (const float*)d_in[11];
  const float* f2b   = (const float*)d_in[12];

  char* ws = (char*)d_ws;
  ushort* wcat = (ushort*)(ws + 0);            // 786432 bf16
  float*  xT   = (float*)(ws + 1572864);       // 802816 f32 (LN1 input copy)
  ushort* t    = (ushort*)(ws + 4784128);      // 802816 bf16 (t1)
  ushort* qh   = (ushort*)(ws + 6389760);      // qkv [3136][768]
  float*  x1   = (float*)(ws + 12812288);      // 802816 f32 (post-attn resid)

  const ushort* qw_bf = wcat;
  const ushort* pw_bf = wcat + 196608;
  const ushort* f1_bf = wcat + 262144;
  const ushort* f2_bf = wcat + 524288;
  float* outf = (float*)d_out;

  hipLaunchKernelGGL(prep_kernel, dim3(3268), dim3(256), 0, stream,
                     x, n1w, n1b, qkvw, projw, f1w, f2w, xT, t, wcat);
  hipLaunchKernelGGL(qkv_kernel, dim3(12, 49), dim3(256), 0, stream,
                     t, qw_bf, qkvb, qh);
  hipLaunchKernelGGL(attnproj_kernel, dim3(196), dim3(256), 0, stream,
                     qh, pw_bf, projb, xT, x1);
  hipLaunchKernelGGL(mlp_kernel, dim3(196), dim3(256), 0, stream,
                     x1, f1_bf, f1b, f2_bf, f2b, n2w, n2b, outf);
}

// Round 8
// 126.329 us; speedup vs baseline: 1.1679x; 1.1489x over previous
//
#include <hip/hip_runtime.h>
#include <math.h>

// ---------------------------------------------------------------------------
// LocalTransformerBlock2d: B=1, C=256, H=W=56 (N=3136), 8 heads x d=32,
// 7x7 local window. fp32 in/out; bf16 MFMA GEMMs.
// 3 stream-ordered kernels:
//   prep(cvt+LN1T) -> qkv -> attnmlp (attn+proj+LN2+fc1+gelu+fc2+resid,
//                                     one 512-thread block per 16 pixels)
// Ledger: 2x42us harness poison fills are in the timed window; pipeline was
// ~61us at R7. R7 lesson: 196-block kernels run 1 blk/CU; 256-thr blocks =
// 1 wave/SIMD = zero latency hiding. This round: 512 thr (2 waves/SIMD),
// full block-local fusion (x1 never leaves LDS/regs), per-wave slab DMA.
// ---------------------------------------------------------------------------

typedef unsigned int uint;
typedef unsigned short ushort;
typedef unsigned long long u64;
typedef __attribute__((ext_vector_type(8))) short short8;   // 8 bf16
typedef __attribute__((ext_vector_type(4))) float floatx4;  // MFMA acc
typedef __attribute__((ext_vector_type(4))) unsigned short ushort4v;

#define AS1(p) (const __attribute__((address_space(1))) void*)(p)
#define AS3(p) (__attribute__((address_space(3))) void*)(p)

__device__ __forceinline__ float bf2f(ushort u) {
  union { uint i; float f; } v; v.i = ((uint)u) << 16; return v.f;
}
__device__ __forceinline__ ushort f2bf(float f) {
  union { float f; uint i; } v; v.f = f;
  uint u = v.i;
  return (ushort)((u + 0x7fffu + ((u >> 16) & 1u)) >> 16);
}

// Stage a 64-row x 256-col bf16 panel into LDS with XOR swizzle.
__device__ __forceinline__ void stage64(const ushort* src, int kstride,
                                        ushort* dstBase, int tid) {
  const int srow = tid >> 5;
  const int scb  = (tid & 31) ^ srow;
  const ushort* g = src + (size_t)srow * kstride + scb * 8;
  ushort* d = dstBase + tid * 8;
  #pragma unroll
  for (int r = 0; r < 8; ++r) {
    __builtin_amdgcn_global_load_lds(AS1(g), AS3(d), 16, 0, 0);
    g += 8 * kstride;
    d += 2048;
  }
}

__device__ __forceinline__ void compute64(const ushort* As, const ushort* Bs,
                                          int w, int lane, floatx4 acc[4]) {
  const int fm = lane & 15;
  const int q  = lane >> 4;
  const int swz = fm & 7;
  const int arow = (w * 16 + fm) * 256;
  #pragma unroll
  for (int kt = 0; kt < 8; ++kt) {
    const int blk = ((kt * 4 + q) ^ swz) * 8;
    short8 af = *(const short8*)&As[arow + blk];
    #pragma unroll
    for (int nt = 0; nt < 4; ++nt) {
      short8 bfr = *(const short8*)&Bs[(nt * 16 + fm) * 256 + blk];
      acc[nt] = __builtin_amdgcn_mfma_f32_16x16x32_bf16(af, bfr, acc[nt], 0, 0, 0);
    }
  }
}

// ---------------------------------------------------------------------------
// prep: blocks 0..195 LN1+transpose (16 px each); blocks 196+ weight cvt.
// ---------------------------------------------------------------------------
__global__ __launch_bounds__(256) void prep_kernel(
    const float* __restrict__ x, const float* __restrict__ n1w,
    const float* __restrict__ n1b,
    const float* __restrict__ qkvw, const float* __restrict__ projw,
    const float* __restrict__ f1w, const float* __restrict__ f2w,
    float* __restrict__ xT, ushort* __restrict__ t1, ushort* __restrict__ wcat)
{
  const int tid = threadIdx.x;
  const int bid = blockIdx.x;
  if (bid >= 196) {
    int idx = (bid - 196) * 256 + tid;
    float v;
    if (idx < 196608)       v = qkvw[idx];
    else if (idx < 262144)  v = projw[idx - 196608];
    else if (idx < 524288)  v = f1w[idx - 262144];
    else                    v = f2w[idx - 524288];
    wcat[idx] = f2bf(v);
    return;
  }
  __shared__ float tile[256 * 17];
  __shared__ float red[2][16][16];
  __shared__ float mu[16], rsv[16];
  const int n0 = bid * 16;
  const int px = tid & 15, grp = tid >> 4;
  #pragma unroll 4
  for (int it = 0; it < 16; ++it) {
    int c = it * 16 + grp;
    tile[c * 17 + px] = x[(size_t)c * 3136 + n0 + px];
  }
  __syncthreads();
  float s = 0.f, ss = 0.f;
  #pragma unroll
  for (int i = 0; i < 16; ++i) {
    float v = tile[(grp * 16 + i) * 17 + px];
    s += v; ss += v * v;
  }
  red[0][px][grp] = s; red[1][px][grp] = ss;
  __syncthreads();
  if (tid < 16) {
    float s2 = 0.f, ss2 = 0.f;
    #pragma unroll
    for (int g = 0; g < 16; ++g) { s2 += red[0][tid][g]; ss2 += red[1][tid][g]; }
    float m = s2 * (1.f / 256.f);
    float var = ss2 * (1.f / 256.f) - m * m;
    mu[tid] = m;
    rsv[tid] = rsqrtf(var + 1e-5f);
  }
  __syncthreads();
  const float wc = n1w[tid], bc = n1b[tid];
  #pragma unroll 4
  for (int p = 0; p < 16; ++p) {
    float v = tile[tid * 17 + p];
    xT[(size_t)(n0 + p) * 256 + tid] = v;
    t1[(size_t)(n0 + p) * 256 + tid] = f2bf((v - mu[p]) * rsv[p] * wc + bc);
  }
}

// ---------------------------------------------------------------------------
// qkv: [3136,256] @ [768,256]^T + bias (q scaled). grid (12,49).
// ---------------------------------------------------------------------------
__global__ __launch_bounds__(256, 2) void qkv_kernel(
    const ushort* __restrict__ A, const ushort* __restrict__ B,
    const float* __restrict__ bias, ushort* __restrict__ out)
{
  __shared__ ushort As[16384], Bs[16384];
  const int tid = threadIdx.x, lane = tid & 63, w = tid >> 6;
  const int m0 = blockIdx.y * 64, n0 = blockIdx.x * 64;
  floatx4 acc[4] = {{0.f,0.f,0.f,0.f},{0.f,0.f,0.f,0.f},
                    {0.f,0.f,0.f,0.f},{0.f,0.f,0.f,0.f}};
  stage64(A + (size_t)m0 * 256, 256, As, tid);
  stage64(B + (size_t)n0 * 256, 256, Bs, tid);
  asm volatile("s_waitcnt vmcnt(0)" ::: "memory");
  __syncthreads();
  compute64(As, Bs, w, lane, acc);
  const int fm = lane & 15, q4 = (lane >> 4) * 4;
  #pragma unroll
  for (int nt = 0; nt < 4; ++nt)
    #pragma unroll
    for (int r = 0; r < 4; ++r) {
      int m = m0 + w * 16 + q4 + r;
      int n = n0 + nt * 16 + fm;
      float v = acc[nt][r] + bias[n];
      if (n < 256) v *= 0.17677669529663687f;   // 1/sqrt(32) on q
      out[(size_t)m * 768 + n] = f2bf(v);
    }
}

// ---------------------------------------------------------------------------
// attnmlp: 4x4 query tile per block (grid 196), 512 threads (2 waves/SIMD).
// Phases: halo -> scores -> PV -> proj(+resid -> x1s LDS) -> LN2 -> fc1+gelu
//         -> fc2(+reg-resid) -> out. Per-wave slab DMA, no barriers in GEMMs.
// LDS (byte offsets):
//  attn: Kh@0 (52000) | Vh@52000 (51200) | pr@103200 (32768) | aas@136000 (8448)
//  proj: pslab@0 (32768, Kh dead) | x1s@103200 f32[16][264] (pr dead)
//  mlp : hbuf@0 (32768) | fslab@32768 (65536, Vh dead) | t2s@120096 (8192)
//        pstat@128288 | stats@129312
// ---------------------------------------------------------------------------
#define AM_SMEM 144448

__global__ __launch_bounds__(512, 1) void attnmlp_kernel(
    const ushort* __restrict__ qkv, const ushort* __restrict__ pw_bf,
    const float* __restrict__ projb, const float* __restrict__ xT,
    const ushort* __restrict__ f1_bf, const float* __restrict__ f1b,
    const ushort* __restrict__ f2_bf, const float* __restrict__ f2b,
    const float* __restrict__ n2w, const float* __restrict__ n2b,
    float* __restrict__ outf)
{
  __shared__ __align__(16) char smem[AM_SMEM];
  ushort* Kh    = (ushort*)smem;
  ushort* Vh    = (ushort*)(smem + 52000);
  float*  pr    = (float*)(smem + 103200);
  ushort* aas   = (ushort*)(smem + 136000);      // [16][264]
  ushort* pslab = (ushort*)smem;                 // 8 x (2 x 1024 elems)
  float*  x1s   = (float*)(smem + 103200);       // [16][264] f32
  ushort* hbuf  = (ushort*)smem;                 // [16][1024]
  ushort* fslab = (ushort*)(smem + 32768);       // 8 x 4096 elems
  ushort* t2s   = (ushort*)(smem + 120096);      // [16][256]
  float*  pstat = (float*)(smem + 128288);       // [8][16][2]
  float*  stats = (float*)(smem + 129312);       // [16][2]

  const int tid = threadIdx.x;
  const int wv = tid >> 6, lane = tid & 63;
  const int fm = lane & 15, q = lane >> 4;
  const int l4 = lane >> 2, lb = lane & 3;
  const int i0 = (blockIdx.x / 14) * 4, j0 = (blockIdx.x % 14) * 4;

  // ---- halo load (zero-fill out-of-image) ----
  for (int s = tid; s < 3200; s += 512) {
    int p = s >> 5, ck = s & 31;
    int ii = i0 - 3 + p / 10, jj = j0 - 3 + p % 10;
    if (ii >= 0 && ii < 56 && jj >= 0 && jj < 56) {
      const ushort* kr = qkv + (size_t)(ii * 56 + jj) * 768 + 256 + ck * 8;
      short8 kv = *(const short8*)kr;
      u64 lo = ((const u64*)&kv)[0], hi = ((const u64*)&kv)[1];
      *(u64*)&Kh[p * 260 + ck * 8] = lo;
      *(u64*)&Kh[p * 260 + ck * 8 + 4] = hi;
      *(short8*)&Vh[p * 256 + ck * 8] = *(const short8*)(kr + 256);
    } else {
      *(u64*)&Kh[p * 260 + ck * 8] = 0ull;
      *(u64*)&Kh[p * 260 + ck * 8 + 4] = 0ull;
      short8 z = {0, 0, 0, 0, 0, 0, 0, 0};
      *(short8*)&Vh[p * 256 + ck * 8] = z;
    }
  }
  __syncthreads();

  // ---- scores + softmax: wave wv owns queries 2wv, 2wv+1 ----
  {
    const int h = lane >> 3, mg = lane & 7;
    #pragma unroll
    for (int qq = 0; qq < 2; ++qq) {
      const int p = wv * 2 + qq;
      const int qi = p >> 2, qj = p & 3;
      const int iq = i0 + qi, jq = j0 + qj;
      const ushort* qp = qkv + (size_t)(iq * 56 + jq) * 768 + h * 32;
      float qf[32];
      #pragma unroll
      for (int u = 0; u < 4; ++u) {
        short8 qv = *(const short8*)(qp + u * 8);
        #pragma unroll
        for (int e = 0; e < 8; ++e) qf[u * 8 + e] = bf2f((ushort)qv[e]);
      }
      float sv[7];
      float mx = -1e30f;
      #pragma unroll
      for (int k = 0; k < 7; ++k) {
        int m = mg + 8 * k;
        float s = -1e30f;
        if (m < 49) {
          int mi = m / 7, mj = m % 7;
          int ii = iq + mi - 3, jj = jq + mj - 3;
          if (ii >= 0 && ii < 56 && jj >= 0 && jj < 56) {
            int hrow = (qi + mi) * 10 + (qj + mj);
            const u64* k8 = (const u64*)&Kh[hrow * 260 + h * 32];
            float a = 0.f;
            #pragma unroll
            for (int u = 0; u < 8; ++u) {
              u64 kv = k8[u];
              #pragma unroll
              for (int e = 0; e < 4; ++e)
                a += qf[u * 4 + e] * bf2f((ushort)(kv >> (16 * e)));
            }
            s = a;
          }
        }
        sv[k] = s;
        mx = fmaxf(mx, s);
      }
      mx = fmaxf(mx, __shfl_xor(mx, 1));
      mx = fmaxf(mx, __shfl_xor(mx, 2));
      mx = fmaxf(mx, __shfl_xor(mx, 4));
      float sm = 0.f;
      #pragma unroll
      for (int k = 0; k < 7; ++k) { sv[k] = __expf(sv[k] - mx); sm += sv[k]; }
      sm += __shfl_xor(sm, 1);
      sm += __shfl_xor(sm, 2);
      sm += __shfl_xor(sm, 4);
      float inv = 1.f / sm;
      #pragma unroll
      for (int k = 0; k < 7; ++k) {
        int m = mg + 8 * k;
        pr[(p * 8 + h) * 64 + m] = sv[k] * inv;
      }
    }
  }
  __syncthreads();     // Kh dead; pr visible

  // per-wave proj slab dbuf in dead Kh region
  ushort* ps0 = pslab + wv * 2048;
  ushort* ps1 = ps0 + 1024;
#define STAGE_P(kt, buf) do { \
    _Pragma("unroll") \
    for (int i_ = 0; i_ < 2; ++i_) { \
      int row_ = i_ * 16 + l4; \
      const ushort* g_ = pw_bf + (size_t)(wv * 32 + row_) * 256 + (kt) * 32 + (lb ^ (row_ & 3)) * 8; \
      __builtin_amdgcn_global_load_lds(AS1(g_), AS3((buf) + i_ * 512 + lane * 8), 16, 0, 0); \
    } } while (0)
  STAGE_P(0, ps0);     // overlaps PV compute

  // ---- PV: thread = (query p = tid>>5, 8-ch group cg), single pass ----
  {
    const int p = tid >> 5, cg = tid & 31, hh = cg >> 2;
    const int qi = p >> 2, qj = p & 3;
    float acc8[8] = {0, 0, 0, 0, 0, 0, 0, 0};
    #pragma unroll
    for (int mi = 0; mi < 7; ++mi)
      #pragma unroll
      for (int mj = 0; mj < 7; ++mj) {
        int m = mi * 7 + mj;
        int hrow = (qi + mi) * 10 + (qj + mj);
        float pm = pr[(p * 8 + hh) * 64 + m];
        short8 v8 = *(const short8*)&Vh[hrow * 256 + cg * 8];
        #pragma unroll
        for (int e = 0; e < 8; ++e)
          acc8[e] += pm * bf2f((ushort)v8[e]);
      }
    short8 o;
    #pragma unroll
    for (int e = 0; e < 8; ++e) o[e] = (short)f2bf(acc8[e]);
    *(short8*)&aas[p * 264 + cg * 8] = o;
  }
  __syncthreads();     // aas visible; pr/Vh dead after this phase

  // ---- proj: wave wv -> out channels wv*32..+31, all 16 px; -> x1s ----
  {
    floatx4 pacc[2] = {{0.f,0.f,0.f,0.f},{0.f,0.f,0.f,0.f}};
    for (int kt = 0; kt < 8; ++kt) {
      ushort* cur = (kt & 1) ? ps1 : ps0;
      ushort* nxt = (kt & 1) ? ps0 : ps1;
      if (kt < 7) {
        STAGE_P(kt + 1, nxt);
        asm volatile("s_waitcnt vmcnt(2)" ::: "memory");
      } else {
        asm volatile("s_waitcnt vmcnt(0)" ::: "memory");
      }
      short8 af = *(const short8*)&aas[fm * 264 + kt * 32 + q * 8];
      #pragma unroll
      for (int nt = 0; nt < 2; ++nt) {
        int r = nt * 16 + fm;
        short8 bfr = *(const short8*)&cur[r * 32 + (q ^ (r & 3)) * 8];
        pacc[nt] = __builtin_amdgcn_mfma_f32_16x16x32_bf16(af, bfr, pacc[nt], 0, 0, 0);
      }
    }
    #pragma unroll
    for (int nt = 0; nt < 2; ++nt) {
      int ch = wv * 32 + nt * 16 + fm;
      #pragma unroll
      for (int r = 0; r < 4; ++r) {
        int px = q * 4 + r;
        int n = (i0 + (px >> 2)) * 56 + j0 + (px & 3);
        x1s[px * 264 + ch] = pacc[nt][r] + projb[ch] + xT[(size_t)n * 256 + ch];
      }
    }
  }
  // kick fc1 slab 0 (fslab region: dead Kh/Vh); lands across the barrier
  ushort* fs0 = fslab + wv * 4096;
  ushort* fs1 = fs0 + 2048;
#define STAGE_F1(c, kt, buf) do { \
    _Pragma("unroll") \
    for (int i_ = 0; i_ < 4; ++i_) { \
      int row_ = i_ * 16 + l4; \
      const ushort* g_ = f1_bf + (size_t)((c) * 64 + row_) * 256 + (kt) * 32 + (lb ^ (row_ & 3)) * 8; \
      __builtin_amdgcn_global_load_lds(AS1(g_), AS3((buf) + i_ * 512 + lane * 8), 16, 0, 0); \
    } } while (0)
  STAGE_F1(wv, 0, fs0);
  __syncthreads();     // x1s complete

  // ---- LN2 from x1s; residual kept in regs (matches fc2 acc layout) ----
  floatx4 xv[2];
  xv[0] = *(const floatx4*)&x1s[fm * 264 + wv * 32 + q * 4];
  xv[1] = *(const floatx4*)&x1s[fm * 264 + wv * 32 + 16 + q * 4];
  {
    float s = 0.f, ss = 0.f;
    #pragma unroll
    for (int nt = 0; nt < 2; ++nt)
      #pragma unroll
      for (int e = 0; e < 4; ++e) { s += xv[nt][e]; ss += xv[nt][e] * xv[nt][e]; }
    s += __shfl_xor(s, 16); ss += __shfl_xor(ss, 16);
    s += __shfl_xor(s, 32); ss += __shfl_xor(ss, 32);
    if (lane < 16) { pstat[(wv * 16 + lane) * 2] = s; pstat[(wv * 16 + lane) * 2 + 1] = ss; }
  }
  __syncthreads();
  if (tid < 16) {
    float s2 = 0.f, ss2 = 0.f;
    #pragma unroll
    for (int ww = 0; ww < 8; ++ww) {
      s2 += pstat[(ww * 16 + tid) * 2];
      ss2 += pstat[(ww * 16 + tid) * 2 + 1];
    }
    float mu = s2 * (1.f / 256.f);
    float var = ss2 * (1.f / 256.f) - mu * mu;
    stats[tid * 2] = mu;
    stats[tid * 2 + 1] = rsqrtf(var + 1e-5f);
  }
  __syncthreads();
  {
    float mu = stats[fm * 2], rs = stats[fm * 2 + 1];
    #pragma unroll
    for (int nt = 0; nt < 2; ++nt) {
      int ch0 = wv * 32 + nt * 16 + q * 4;
      ushort4v o;
      #pragma unroll
      for (int e = 0; e < 4; ++e)
        o[e] = f2bf((xv[nt][e] - mu) * rs * n2w[ch0 + e] + n2b[ch0 + e]);
      int slot = ch0 >> 3;
      *(ushort4v*)&t2s[fm * 256 + ((slot ^ (fm & 7)) * 8) + (ch0 & 7)] = o;
    }
  }
  // preload fc1 bias for this wave's chunks {wv, wv+8}
  float f1br[2][4];
  #pragma unroll
  for (int ci = 0; ci < 2; ++ci)
    #pragma unroll
    for (int nt = 0; nt < 4; ++nt)
      f1br[ci][nt] = f1b[(wv + ci * 8) * 64 + nt * 16 + fm];
  __syncthreads();     // t2s complete

  // ---- fc1: wave wv -> h chunks {wv, wv+8} (64 cols each), gelu -> hbuf ----
  {
    floatx4 fa[4] = {{0.f,0.f,0.f,0.f},{0.f,0.f,0.f,0.f},
                     {0.f,0.f,0.f,0.f},{0.f,0.f,0.f,0.f}};
    for (int sidx = 0; sidx < 16; ++sidx) {
      const int kt = sidx & 7;
      const int ci = sidx >> 3;
      ushort* cur = (sidx & 1) ? fs1 : fs0;
      ushort* nxt = (sidx & 1) ? fs0 : fs1;
      if (sidx < 15) {
        int s1 = sidx + 1;
        STAGE_F1(wv + (s1 >> 3) * 8, s1 & 7, nxt);
        asm volatile("s_waitcnt vmcnt(4)" ::: "memory");
      } else {
        asm volatile("s_waitcnt vmcnt(0)" ::: "memory");
      }
      short8 af = *(const short8*)&t2s[fm * 256 + (((kt * 4 + q) ^ (fm & 7)) * 8)];
      #pragma unroll
      for (int nt = 0; nt < 4; ++nt) {
        int r = nt * 16 + fm;
        short8 bfr = *(const short8*)&cur[r * 32 + (q ^ (r & 3)) * 8];
        fa[nt] = __builtin_amdgcn_mfma_f32_16x16x32_bf16(af, bfr, fa[nt], 0, 0, 0);
      }
      if (kt == 7) {
        #pragma unroll
        for (int nt = 0; nt < 4; ++nt) {
          int hc = (wv + ci * 8) * 64 + nt * 16 + fm;
          #pragma unroll
          for (int r4 = 0; r4 < 4; ++r4) {
            int prow = q * 4 + r4;
            float v = fa[nt][r4] + f1br[ci][nt];
            v = 0.5f * v * (1.0f + erff(v * 0.70710678118654752f));
            hbuf[prow * 1024 + (((hc >> 3) ^ (prow & 7)) * 8) + (hc & 7)] = f2bf(v);
            fa[nt][r4] = 0.f;
          }
        }
      }
    }
  }
  // kick fc2 slab 0 into this wave's (now idle) slab region
  ushort* gs0 = fs0;
  ushort* gs1 = fs0 + 1024;
#define STAGE_F2(kt, buf) do { \
    _Pragma("unroll") \
    for (int i_ = 0; i_ < 2; ++i_) { \
      int row_ = i_ * 16 + l4; \
      const ushort* g_ = f2_bf + (size_t)(wv * 32 + row_) * 1024 + (kt) * 32 + (lb ^ (row_ & 3)) * 8; \
      __builtin_amdgcn_global_load_lds(AS1(g_), AS3((buf) + i_ * 512 + lane * 8), 16, 0, 0); \
    } } while (0)
  STAGE_F2(0, gs0);
  __syncthreads();     // hbuf complete

  // ---- fc2: wave wv -> out channels wv*32..+31; residual from regs ----
  {
    floatx4 ga[2] = {{0.f,0.f,0.f,0.f},{0.f,0.f,0.f,0.f}};
    for (int kt = 0; kt < 32; ++kt) {
      ushort* cur = (kt & 1) ? gs1 : gs0;
      ushort* nxt = (kt & 1) ? gs0 : gs1;
      if (kt < 31) {
        STAGE_F2(kt + 1, nxt);
        asm volatile("s_waitcnt vmcnt(2)" ::: "memory");
      } else {
        asm volatile("s_waitcnt vmcnt(0)" ::: "memory");
      }
      short8 bfr = *(const short8*)&hbuf[fm * 1024 + (((kt * 4 + q) ^ (fm & 7)) * 8)];
      #pragma unroll
      for (int mt = 0; mt < 2; ++mt) {
        int r = mt * 16 + fm;
        short8 af = *(const short8*)&cur[r * 32 + (q ^ (r & 3)) * 8];
        ga[mt] = __builtin_amdgcn_mfma_f32_16x16x32_bf16(af, bfr, ga[mt], 0, 0, 0);
      }
    }
    #pragma unroll
    for (int mt = 0; mt < 2; ++mt) {
      #pragma unroll
      for (int r4 = 0; r4 < 4; ++r4) {
        int ch = wv * 32 + mt * 16 + q * 4 + r4;
        int n = (i0 + (fm >> 2)) * 56 + j0 + (fm & 3);
        outf[(size_t)ch * 3136 + n] = ga[mt][r4] + f2b[ch] + xv[mt][r4];
      }
    }
  }
#undef STAGE_P
#undef STAGE_F1
#undef STAGE_F2
}

// ---------------------------------------------------------------------------
extern "C" void kernel_launch(void* const* d_in, const int* in_sizes, int n_in,
                              void* d_out, int out_size, void* d_ws, size_t ws_size,
                              hipStream_t stream) {
  const float* x     = (const float*)d_in[0];
  const float* n1w   = (const float*)d_in[1];
  const float* n1b   = (const float*)d_in[2];
  const float* qkvw  = (const float*)d_in[3];
  const float* qkvb  = (const float*)d_in[4];
  const float* projw = (const float*)d_in[5];
  const float* projb = (const float*)d_in[6];
  const float* n2w   = (const float*)d_in[7];
  const float* n2b   = (const float*)d_in[8];
  const float* f1w   = (const float*)d_in[9];
  const float* f1b   = (const float*)d_in[10];
  const float* f2w   = (const float*)d_in[11];
  const float* f2b   = (const float*)d_in[12];

  char* ws = (char*)d_ws;
  ushort* wcat = (ushort*)(ws + 0);            // 786432 bf16
  float*  xT   = (float*)(ws + 1572864);       // 802816 f32 (LN1 input copy)
  ushort* t    = (ushort*)(ws + 4784128);      // 802816 bf16 (t1)
  ushort* qh   = (ushort*)(ws + 6389760);      // qkv [3136][768]

  const ushort* qw_bf = wcat;
  const ushort* pw_bf = wcat + 196608;
  const ushort* f1_bf = wcat + 262144;
  const ushort* f2_bf = wcat + 524288;
  float* outf = (float*)d_out;

  hipLaunchKernelGGL(prep_kernel, dim3(3268), dim3(256), 0, stream,
                     x, n1w, n1b, qkvw, projw, f1w, f2w, xT, t, wcat);
  hipLaunchKernelGGL(qkv_kernel, dim3(12, 49), dim3(256), 0, stream,
                     t, qw_bf, qkvb, qh);
  hipLaunchKernelGGL(attnmlp_kernel, dim3(196), dim3(512), 0, stream,
                     qh, pw_bf, projb, xT, f1_bf, f1b, f2_bf, f2b,
                     n2w, n2b, outf);
}

// Round 9
// 125.861 us; speedup vs baseline: 1.1722x; 1.0037x over previous
//
#include <hip/hip_runtime.h>
#include <math.h>

// ---------------------------------------------------------------------------
// LocalTransformerBlock2d: B=1, C=256, H=W=56 (N=3136), 8 heads x d=32,
// 7x7 local window. fp32 in/out; bf16 MFMA GEMMs.
// 3 stream-ordered kernels:
//   prep(qw cvt + LN1T) -> qkv(+pw/f1/f2 cvt blocks) ->
//   attnmlp (attn+proj+LN2+fc1+gelu+fc2+resid; one 512-thr block / 16 px)
// Ledger: 2x~43.5us harness poison fills inside the timed window (~87us
// structural floor). R8 pipeline ~39us. R9: drop xT (resid read from x as
// float4), pr stride 64->67 (PV bank-conflict fix), cvt rebalanced.
// ---------------------------------------------------------------------------

typedef unsigned int uint;
typedef unsigned short ushort;
typedef unsigned long long u64;
typedef __attribute__((ext_vector_type(8))) short short8;   // 8 bf16
typedef __attribute__((ext_vector_type(4))) float floatx4;  // MFMA acc
typedef __attribute__((ext_vector_type(4))) unsigned short ushort4v;

#define AS1(p) (const __attribute__((address_space(1))) void*)(p)
#define AS3(p) (__attribute__((address_space(3))) void*)(p)

__device__ __forceinline__ float bf2f(ushort u) {
  union { uint i; float f; } v; v.i = ((uint)u) << 16; return v.f;
}
__device__ __forceinline__ ushort f2bf(float f) {
  union { float f; uint i; } v; v.f = f;
  uint u = v.i;
  return (ushort)((u + 0x7fffu + ((u >> 16) & 1u)) >> 16);
}

// Stage a 64-row x 256-col bf16 panel into LDS with XOR swizzle.
__device__ __forceinline__ void stage64(const ushort* src, int kstride,
                                        ushort* dstBase, int tid) {
  const int srow = tid >> 5;
  const int scb  = (tid & 31) ^ srow;
  const ushort* g = src + (size_t)srow * kstride + scb * 8;
  ushort* d = dstBase + tid * 8;
  #pragma unroll
  for (int r = 0; r < 8; ++r) {
    __builtin_amdgcn_global_load_lds(AS1(g), AS3(d), 16, 0, 0);
    g += 8 * kstride;
    d += 2048;
  }
}

__device__ __forceinline__ void compute64(const ushort* As, const ushort* Bs,
                                          int w, int lane, floatx4 acc[4]) {
  const int fm = lane & 15;
  const int q  = lane >> 4;
  const int swz = fm & 7;
  const int arow = (w * 16 + fm) * 256;
  #pragma unroll
  for (int kt = 0; kt < 8; ++kt) {
    const int blk = ((kt * 4 + q) ^ swz) * 8;
    short8 af = *(const short8*)&As[arow + blk];
    #pragma unroll
    for (int nt = 0; nt < 4; ++nt) {
      short8 bfr = *(const short8*)&Bs[(nt * 16 + fm) * 256 + blk];
      acc[nt] = __builtin_amdgcn_mfma_f32_16x16x32_bf16(af, bfr, acc[nt], 0, 0, 0);
    }
  }
}

// ---------------------------------------------------------------------------
// prep: blocks 0..195 LN1+transpose (16 px each); blocks 196..963 qkv-w cvt.
// ---------------------------------------------------------------------------
__global__ __launch_bounds__(256) void prep_kernel(
    const float* __restrict__ x, const float* __restrict__ n1w,
    const float* __restrict__ n1b, const float* __restrict__ qkvw,
    ushort* __restrict__ t1, ushort* __restrict__ wcat)
{
  const int tid = threadIdx.x;
  const int bid = blockIdx.x;
  if (bid >= 196) {
    int idx = (bid - 196) * 256 + tid;       // < 196608
    wcat[idx] = f2bf(qkvw[idx]);
    return;
  }
  __shared__ float tile[256 * 17];
  __shared__ float red[2][16][16];
  __shared__ float mu[16], rsv[16];
  const int n0 = bid * 16;
  const int px = tid & 15, grp = tid >> 4;
  #pragma unroll 4
  for (int it = 0; it < 16; ++it) {
    int c = it * 16 + grp;
    tile[c * 17 + px] = x[(size_t)c * 3136 + n0 + px];
  }
  __syncthreads();
  float s = 0.f, ss = 0.f;
  #pragma unroll
  for (int i = 0; i < 16; ++i) {
    float v = tile[(grp * 16 + i) * 17 + px];
    s += v; ss += v * v;
  }
  red[0][px][grp] = s; red[1][px][grp] = ss;
  __syncthreads();
  if (tid < 16) {
    float s2 = 0.f, ss2 = 0.f;
    #pragma unroll
    for (int g = 0; g < 16; ++g) { s2 += red[0][tid][g]; ss2 += red[1][tid][g]; }
    float m = s2 * (1.f / 256.f);
    float var = ss2 * (1.f / 256.f) - m * m;
    mu[tid] = m;
    rsv[tid] = rsqrtf(var + 1e-5f);
  }
  __syncthreads();
  const float wc = n1w[tid], bc = n1b[tid];
  #pragma unroll 4
  for (int p = 0; p < 16; ++p) {
    float v = tile[tid * 17 + p];
    t1[(size_t)(n0 + p) * 256 + tid] = f2bf((v - mu[p]) * rsv[p] * wc + bc);
  }
}

// ---------------------------------------------------------------------------
// qkv: grid (12, 241). y<49: GEMM [3136,256]@[768,256]^T + bias (q scaled).
// y>=49: cvt blocks for pw|f1|f2 (589824 elems), consumed by attnmlp later.
// ---------------------------------------------------------------------------
__global__ __launch_bounds__(256, 2) void qkv_kernel(
    const ushort* __restrict__ A, const ushort* __restrict__ B,
    const float* __restrict__ bias, ushort* __restrict__ out,
    const float* __restrict__ projw, const float* __restrict__ f1w,
    const float* __restrict__ f2w, ushort* __restrict__ wcat)
{
  const int tid = threadIdx.x;
  if (blockIdx.y >= 49) {
    int c = (blockIdx.y - 49) * 12 + blockIdx.x;     // 0..2303
    int idx = c * 256 + tid;                         // < 589824
    float v;
    if (idx < 65536)        v = projw[idx];
    else if (idx < 327680)  v = f1w[idx - 65536];
    else                    v = f2w[idx - 327680];
    wcat[196608 + idx] = f2bf(v);
    return;
  }
  __shared__ ushort As[16384], Bs[16384];
  const int lane = tid & 63, w = tid >> 6;
  const int m0 = blockIdx.y * 64, n0 = blockIdx.x * 64;
  floatx4 acc[4] = {{0.f,0.f,0.f,0.f},{0.f,0.f,0.f,0.f},
                    {0.f,0.f,0.f,0.f},{0.f,0.f,0.f,0.f}};
  stage64(A + (size_t)m0 * 256, 256, As, tid);
  stage64(B + (size_t)n0 * 256, 256, Bs, tid);
  asm volatile("s_waitcnt vmcnt(0)" ::: "memory");
  __syncthreads();
  compute64(As, Bs, w, lane, acc);
  const int fm = lane & 15, q4 = (lane >> 4) * 4;
  #pragma unroll
  for (int nt = 0; nt < 4; ++nt)
    #pragma unroll
    for (int r = 0; r < 4; ++r) {
      int m = m0 + w * 16 + q4 + r;
      int n = n0 + nt * 16 + fm;
      float v = acc[nt][r] + bias[n];
      if (n < 256) v *= 0.17677669529663687f;   // 1/sqrt(32) on q
      out[(size_t)m * 768 + n] = f2bf(v);
    }
}

// ---------------------------------------------------------------------------
// attnmlp: 4x4 query tile per block (grid 196), 512 threads (2 waves/SIMD).
// LDS (byte offsets):
//  attn: Kh@0 (52000) | Vh@52000 (51200) | pr@103200 f32 stride67 (34304)
//        aas@137504 (8448)
//  proj: pslab@0 (Kh dead) | x1s@103200 f32[16][264] (16896, pr footprint)
//  mlp : hbuf@0 (32768) | fslab@32768 (65536) | t2s@120096 (8192)
//        pstat@128288 | stats@129312
// pr stride 67: PV reads conflict-free (16 banks, 4-lane bcast); writes <=2-way.
// ---------------------------------------------------------------------------
#define AM_SMEM 145952

__global__ __launch_bounds__(512, 1) void attnmlp_kernel(
    const ushort* __restrict__ qkv, const ushort* __restrict__ pw_bf,
    const float* __restrict__ projb, const float* __restrict__ x,
    const ushort* __restrict__ f1_bf, const float* __restrict__ f1b,
    const ushort* __restrict__ f2_bf, const float* __restrict__ f2b,
    const float* __restrict__ n2w, const float* __restrict__ n2b,
    float* __restrict__ outf)
{
  __shared__ __align__(16) char smem[AM_SMEM];
  ushort* Kh    = (ushort*)smem;
  ushort* Vh    = (ushort*)(smem + 52000);
  float*  pr    = (float*)(smem + 103200);       // [16*8][67]
  ushort* aas   = (ushort*)(smem + 137504);      // [16][264]
  ushort* pslab = (ushort*)smem;                 // proj slabs (Kh dead)
  float*  x1s   = (float*)(smem + 103200);       // [16][264] f32 (pr dead)
  ushort* hbuf  = (ushort*)smem;                 // [16][1024]
  ushort* fslab = (ushort*)(smem + 32768);       // 8 x 4096 elems
  ushort* t2s   = (ushort*)(smem + 120096);      // [16][256]
  float*  pstat = (float*)(smem + 128288);       // [8][16][2]
  float*  stats = (float*)(smem + 129312);       // [16][2]

  const int tid = threadIdx.x;
  const int wv = tid >> 6, lane = tid & 63;
  const int fm = lane & 15, q = lane >> 4;
  const int l4 = lane >> 2, lb = lane & 3;
  const int i0 = (blockIdx.x / 14) * 4, j0 = (blockIdx.x % 14) * 4;

  // ---- halo load (zero-fill out-of-image) ----
  for (int s = tid; s < 3200; s += 512) {
    int p = s >> 5, ck = s & 31;
    int ii = i0 - 3 + p / 10, jj = j0 - 3 + p % 10;
    if (ii >= 0 && ii < 56 && jj >= 0 && jj < 56) {
      const ushort* kr = qkv + (size_t)(ii * 56 + jj) * 768 + 256 + ck * 8;
      short8 kv = *(const short8*)kr;
      u64 lo = ((const u64*)&kv)[0], hi = ((const u64*)&kv)[1];
      *(u64*)&Kh[p * 260 + ck * 8] = lo;
      *(u64*)&Kh[p * 260 + ck * 8 + 4] = hi;
      *(short8*)&Vh[p * 256 + ck * 8] = *(const short8*)(kr + 256);
    } else {
      *(u64*)&Kh[p * 260 + ck * 8] = 0ull;
      *(u64*)&Kh[p * 260 + ck * 8 + 4] = 0ull;
      short8 z = {0, 0, 0, 0, 0, 0, 0, 0};
      *(short8*)&Vh[p * 256 + ck * 8] = z;
    }
  }
  __syncthreads();

  // ---- scores + softmax: wave wv owns queries 2wv, 2wv+1 ----
  {
    const int h = lane >> 3, mg = lane & 7;
    #pragma unroll
    for (int qq = 0; qq < 2; ++qq) {
      const int p = wv * 2 + qq;
      const int qi = p >> 2, qj = p & 3;
      const int iq = i0 + qi, jq = j0 + qj;
      const ushort* qp = qkv + (size_t)(iq * 56 + jq) * 768 + h * 32;
      float qf[32];
      #pragma unroll
      for (int u = 0; u < 4; ++u) {
        short8 qv = *(const short8*)(qp + u * 8);
        #pragma unroll
        for (int e = 0; e < 8; ++e) qf[u * 8 + e] = bf2f((ushort)qv[e]);
      }
      float sv[7];
      float mx = -1e30f;
      #pragma unroll
      for (int k = 0; k < 7; ++k) {
        int m = mg + 8 * k;
        float s = -1e30f;
        if (m < 49) {
          int mi = m / 7, mj = m % 7;
          int ii = iq + mi - 3, jj = jq + mj - 3;
          if (ii >= 0 && ii < 56 && jj >= 0 && jj < 56) {
            int hrow = (qi + mi) * 10 + (qj + mj);
            const u64* k8 = (const u64*)&Kh[hrow * 260 + h * 32];
            float a = 0.f;
            #pragma unroll
            for (int u = 0; u < 8; ++u) {
              u64 kv = k8[u];
              #pragma unroll
              for (int e = 0; e < 4; ++e)
                a += qf[u * 4 + e] * bf2f((ushort)(kv >> (16 * e)));
            }
            s = a;
          }
        }
        sv[k] = s;
        mx = fmaxf(mx, s);
      }
      mx = fmaxf(mx, __shfl_xor(mx, 1));
      mx = fmaxf(mx, __shfl_xor(mx, 2));
      mx = fmaxf(mx, __shfl_xor(mx, 4));
      float sm = 0.f;
      #pragma unroll
      for (int k = 0; k < 7; ++k) { sv[k] = __expf(sv[k] - mx); sm += sv[k]; }
      sm += __shfl_xor(sm, 1);
      sm += __shfl_xor(sm, 2);
      sm += __shfl_xor(sm, 4);
      float inv = 1.f / sm;
      #pragma unroll
      for (int k = 0; k < 7; ++k) {
        int m = mg + 8 * k;
        pr[(p * 8 + h) * 67 + m] = sv[k] * inv;
      }
    }
  }
  __syncthreads();     // Kh dead; pr visible

  // per-wave proj slab dbuf in dead Kh region
  ushort* ps0 = pslab + wv * 2048;
  ushort* ps1 = ps0 + 1024;
#define STAGE_P(kt, buf) do { \
    _Pragma("unroll") \
    for (int i_ = 0; i_ < 2; ++i_) { \
      int row_ = i_ * 16 + l4; \
      const ushort* g_ = pw_bf + (size_t)(wv * 32 + row_) * 256 + (kt) * 32 + (lb ^ (row_ & 3)) * 8; \
      __builtin_amdgcn_global_load_lds(AS1(g_), AS3((buf) + i_ * 512 + lane * 8), 16, 0, 0); \
    } } while (0)
  STAGE_P(0, ps0);     // overlaps PV compute

  // ---- PV: thread = (query p = tid>>5, 8-ch group cg), single pass ----
  {
    const int p = tid >> 5, cg = tid & 31, hh = cg >> 2;
    const int qi = p >> 2, qj = p & 3;
    float acc8[8] = {0, 0, 0, 0, 0, 0, 0, 0};
    #pragma unroll
    for (int mi = 0; mi < 7; ++mi)
      #pragma unroll
      for (int mj = 0; mj < 7; ++mj) {
        int m = mi * 7 + mj;
        int hrow = (qi + mi) * 10 + (qj + mj);
        float pm = pr[(p * 8 + hh) * 67 + m];
        short8 v8 = *(const short8*)&Vh[hrow * 256 + cg * 8];
        #pragma unroll
        for (int e = 0; e < 8; ++e)
          acc8[e] += pm * bf2f((ushort)v8[e]);
      }
    short8 o;
    #pragma unroll
    for (int e = 0; e < 8; ++e) o[e] = (short)f2bf(acc8[e]);
    *(short8*)&aas[p * 264 + cg * 8] = o;
  }
  __syncthreads();     // aas visible; pr/Vh dead after this phase

  // ---- proj: wave wv -> out ch wv*32..+31, all 16 px; resid from x ----
  {
    floatx4 pacc[2] = {{0.f,0.f,0.f,0.f},{0.f,0.f,0.f,0.f}};
    for (int kt = 0; kt < 8; ++kt) {
      ushort* cur = (kt & 1) ? ps1 : ps0;
      ushort* nxt = (kt & 1) ? ps0 : ps1;
      if (kt < 7) {
        STAGE_P(kt + 1, nxt);
        asm volatile("s_waitcnt vmcnt(2)" ::: "memory");
      } else {
        asm volatile("s_waitcnt vmcnt(0)" ::: "memory");
      }
      short8 af = *(const short8*)&aas[fm * 264 + kt * 32 + q * 8];
      #pragma unroll
      for (int nt = 0; nt < 2; ++nt) {
        int r = nt * 16 + fm;
        short8 bfr = *(const short8*)&cur[r * 32 + (q ^ (r & 3)) * 8];
        pacc[nt] = __builtin_amdgcn_mfma_f32_16x16x32_bf16(af, bfr, pacc[nt], 0, 0, 0);
      }
    }
    #pragma unroll
    for (int nt = 0; nt < 2; ++nt) {
      int ch = wv * 32 + nt * 16 + fm;
      // residual: 4 consecutive pixels (i0+q, j0..j0+3) of channel ch
      floatx4 rx = *(const floatx4*)(x + (size_t)ch * 3136 + (i0 + q) * 56 + j0);
      #pragma unroll
      for (int r = 0; r < 4; ++r) {
        int px = q * 4 + r;
        x1s[px * 264 + ch] = pacc[nt][r] + projb[ch] + rx[r];
      }
    }
  }
  // kick fc1 slab 0 (fslab region: dead Kh/Vh); lands across the barrier
  ushort* fs0 = fslab + wv * 4096;
  ushort* fs1 = fs0 + 2048;
#define STAGE_F1(c, kt, buf) do { \
    _Pragma("unroll") \
    for (int i_ = 0; i_ < 4; ++i_) { \
      int row_ = i_ * 16 + l4; \
      const ushort* g_ = f1_bf + (size_t)((c) * 64 + row_) * 256 + (kt) * 32 + (lb ^ (row_ & 3)) * 8; \
      __builtin_amdgcn_global_load_lds(AS1(g_), AS3((buf) + i_ * 512 + lane * 8), 16, 0, 0); \
    } } while (0)
  STAGE_F1(wv, 0, fs0);
  __syncthreads();     // x1s complete

  // ---- LN2 from x1s; residual kept in regs (matches fc2 acc layout) ----
  floatx4 xv[2];
  xv[0] = *(const floatx4*)&x1s[fm * 264 + wv * 32 + q * 4];
  xv[1] = *(const floatx4*)&x1s[fm * 264 + wv * 32 + 16 + q * 4];
  {
    float s = 0.f, ss = 0.f;
    #pragma unroll
    for (int nt = 0; nt < 2; ++nt)
      #pragma unroll
      for (int e = 0; e < 4; ++e) { s += xv[nt][e]; ss += xv[nt][e] * xv[nt][e]; }
    s += __shfl_xor(s, 16); ss += __shfl_xor(ss, 16);
    s += __shfl_xor(s, 32); ss += __shfl_xor(ss, 32);
    if (lane < 16) { pstat[(wv * 16 + lane) * 2] = s; pstat[(wv * 16 + lane) * 2 + 1] = ss; }
  }
  __syncthreads();
  if (tid < 16) {
    float s2 = 0.f, ss2 = 0.f;
    #pragma unroll
    for (int ww = 0; ww < 8; ++ww) {
      s2 += pstat[(ww * 16 + tid) * 2];
      ss2 += pstat[(ww * 16 + tid) * 2 + 1];
    }
    float mu = s2 * (1.f / 256.f);
    float var = ss2 * (1.f / 256.f) - mu * mu;
    stats[tid * 2] = mu;
    stats[tid * 2 + 1] = rsqrtf(var + 1e-5f);
  }
  __syncthreads();
  {
    float mu = stats[fm * 2], rs = stats[fm * 2 + 1];
    #pragma unroll
    for (int nt = 0; nt < 2; ++nt) {
      int ch0 = wv * 32 + nt * 16 + q * 4;
      ushort4v o;
      #pragma unroll
      for (int e = 0; e < 4; ++e)
        o[e] = f2bf((xv[nt][e] - mu) * rs * n2w[ch0 + e] + n2b[ch0 + e]);
      int slot = ch0 >> 3;
      *(ushort4v*)&t2s[fm * 256 + ((slot ^ (fm & 7)) * 8) + (ch0 & 7)] = o;
    }
  }
  // preload fc1 bias for this wave's chunks {wv, wv+8}
  float f1br[2][4];
  #pragma unroll
  for (int ci = 0; ci < 2; ++ci)
    #pragma unroll
    for (int nt = 0; nt < 4; ++nt)
      f1br[ci][nt] = f1b[(wv + ci * 8) * 64 + nt * 16 + fm];
  __syncthreads();     // t2s complete

  // ---- fc1: wave wv -> h chunks {wv, wv+8} (64 cols each), gelu -> hbuf ----
  {
    floatx4 fa[4] = {{0.f,0.f,0.f,0.f},{0.f,0.f,0.f,0.f},
                     {0.f,0.f,0.f,0.f},{0.f,0.f,0.f,0.f}};
    for (int sidx = 0; sidx < 16; ++sidx) {
      const int kt = sidx & 7;
      const int ci = sidx >> 3;
      ushort* cur = (sidx & 1) ? fs1 : fs0;
      ushort* nxt = (sidx & 1) ? fs0 : fs1;
      if (sidx < 15) {
        int s1 = sidx + 1;
        STAGE_F1(wv + (s1 >> 3) * 8, s1 & 7, nxt);
        asm volatile("s_waitcnt vmcnt(4)" ::: "memory");
      } else {
        asm volatile("s_waitcnt vmcnt(0)" ::: "memory");
      }
      short8 af = *(const short8*)&t2s[fm * 256 + (((kt * 4 + q) ^ (fm & 7)) * 8)];
      #pragma unroll
      for (int nt = 0; nt < 4; ++nt) {
        int r = nt * 16 + fm;
        short8 bfr = *(const short8*)&cur[r * 32 + (q ^ (r & 3)) * 8];
        fa[nt] = __builtin_amdgcn_mfma_f32_16x16x32_bf16(af, bfr, fa[nt], 0, 0, 0);
      }
      if (kt == 7) {
        #pragma unroll
        for (int nt = 0; nt < 4; ++nt) {
          int hc = (wv + ci * 8) * 64 + nt * 16 + fm;
          #pragma unroll
          for (int r4 = 0; r4 < 4; ++r4) {
            int prow = q * 4 + r4;
            float v = fa[nt][r4] + f1br[ci][nt];
            v = 0.5f * v * (1.0f + erff(v * 0.70710678118654752f));
            hbuf[prow * 1024 + (((hc >> 3) ^ (prow & 7)) * 8) + (hc & 7)] = f2bf(v);
            fa[nt][r4] = 0.f;
          }
        }
      }
    }
  }
  // kick fc2 slab 0 into this wave's (now idle) slab region
  ushort* gs0 = fs0;
  ushort* gs1 = fs0 + 1024;
#define STAGE_F2(kt, buf) do { \
    _Pragma("unroll") \
    for (int i_ = 0; i_ < 2; ++i_) { \
      int row_ = i_ * 16 + l4; \
      const ushort* g_ = f2_bf + (size_t)(wv * 32 + row_) * 1024 + (kt) * 32 + (lb ^ (row_ & 3)) * 8; \
      __builtin_amdgcn_global_load_lds(AS1(g_), AS3((buf) + i_ * 512 + lane * 8), 16, 0, 0); \
    } } while (0)
  STAGE_F2(0, gs0);
  __syncthreads();     // hbuf complete

  // ---- fc2: wave wv -> out channels wv*32..+31; residual from regs ----
  {
    floatx4 ga[2] = {{0.f,0.f,0.f,0.f},{0.f,0.f,0.f,0.f}};
    for (int kt = 0; kt < 32; ++kt) {
      ushort* cur = (kt & 1) ? gs1 : gs0;
      ushort* nxt = (kt & 1) ? gs0 : gs1;
      if (kt < 31) {
        STAGE_F2(kt + 1, nxt);
        asm volatile("s_waitcnt vmcnt(2)" ::: "memory");
      } else {
        asm volatile("s_waitcnt vmcnt(0)" ::: "memory");
      }
      short8 bfr = *(const short8*)&hbuf[fm * 1024 + (((kt * 4 + q) ^ (fm & 7)) * 8)];
      #pragma unroll
      for (int mt = 0; mt < 2; ++mt) {
        int r = mt * 16 + fm;
        short8 af = *(const short8*)&cur[r * 32 + (q ^ (r & 3)) * 8];
        ga[mt] = __builtin_amdgcn_mfma_f32_16x16x32_bf16(af, bfr, ga[mt], 0, 0, 0);
      }
    }
    #pragma unroll
    for (int mt = 0; mt < 2; ++mt) {
      #pragma unroll
      for (int r4 = 0; r4 < 4; ++r4) {
        int ch = wv * 32 + mt * 16 + q * 4 + r4;
        int n = (i0 + (fm >> 2)) * 56 + j0 + (fm & 3);
        outf[(size_t)ch * 3136 + n] = ga[mt][r4] + f2b[ch] + xv[mt][r4];
      }
    }
  }
#undef STAGE_P
#undef STAGE_F1
#undef STAGE_F2
}

// ---------------------------------------------------------------------------
extern "C" void kernel_launch(void* const* d_in, const int* in_sizes, int n_in,
                              void* d_out, int out_size, void* d_ws, size_t ws_size,
                              hipStream_t stream) {
  const float* x     = (const float*)d_in[0];
  const float* n1w   = (const float*)d_in[1];
  const float* n1b   = (const float*)d_in[2];
  const float* qkvw  = (const float*)d_in[3];
  const float* qkvb  = (const float*)d_in[4];
  const float* projw = (const float*)d_in[5];
  const float* projb = (const float*)d_in[6];
  const float* n2w   = (const float*)d_in[7];
  const float* n2b   = (const float*)d_in[8];
  const float* f1w   = (const float*)d_in[9];
  const float* f1b   = (const float*)d_in[10];
  const float* f2w   = (const float*)d_in[11];
  const float* f2b   = (const float*)d_in[12];

  char* ws = (char*)d_ws;
  ushort* wcat = (ushort*)(ws + 0);            // 786432 bf16
  ushort* t    = (ushort*)(ws + 4784128);      // 802816 bf16 (t1)
  ushort* qh   = (ushort*)(ws + 6389760);      // qkv [3136][768]

  const ushort* qw_bf = wcat;
  const ushort* pw_bf = wcat + 196608;
  const ushort* f1_bf = wcat + 262144;
  const ushort* f2_bf = wcat + 524288;
  float* outf = (float*)d_out;

  hipLaunchKernelGGL(prep_kernel, dim3(964), dim3(256), 0, stream,
                     x, n1w, n1b, qkvw, t, wcat);
  hipLaunchKernelGGL(qkv_kernel, dim3(12, 241), dim3(256), 0, stream,
                     t, qw_bf, qkvb, qh, projw, f1w, f2w, wcat);
  hipLaunchKernelGGL(attnmlp_kernel, dim3(196), dim3(512), 0, stream,
                     qh, pw_bf, projb, x, f1_bf, f1b, f2_bf, f2b,
                     n2w, n2b, outf);
}